// Round 1
// baseline (666.368 us; speedup 1.0000x reference)
//
#include <hip/hip_runtime.h>

#define N_NODES 8192
#define N_EDGES 262144

// ---------------- CSR build ----------------

__global__ void __launch_bounds__(256) count_kernel(const int* __restrict__ dst,
                                                    int* __restrict__ cnt) {
  int e = blockIdx.x * 256 + threadIdx.x;
  atomicAdd(&cnt[dst[e]], 1);
}

__global__ void __launch_bounds__(1024) scan_kernel(const int* __restrict__ cnt,
                                                    int* __restrict__ rp,
                                                    float* __restrict__ dinv) {
  __shared__ int sums[1024];
  const int t = threadIdx.x;
  const int base = t * 8;
  int c[8];
  int s = 0;
#pragma unroll
  for (int i = 0; i < 8; ++i) { c[i] = cnt[base + i]; s += c[i]; }
  sums[t] = s;
  __syncthreads();
  for (int off = 1; off < 1024; off <<= 1) {
    int v = (t >= off) ? sums[t - off] : 0;
    __syncthreads();
    sums[t] += v;
    __syncthreads();
  }
  int run = (t == 0) ? 0 : sums[t - 1];
#pragma unroll
  for (int i = 0; i < 8; ++i) {
    rp[base + i] = run;
    run += c[i];
    dinv[base + i] = rsqrtf((float)(c[i] + 1));  // +1 self-loop; deg>=1 always
  }
  if (t == 1023) rp[N_NODES] = run;
}

__global__ void __launch_bounds__(256) fill_kernel(const int* __restrict__ src,
                                                   const int* __restrict__ dst,
                                                   const int* __restrict__ rp,
                                                   const float* __restrict__ dinv,
                                                   int* __restrict__ cur,
                                                   int* __restrict__ col,
                                                   float* __restrict__ wgt) {
  int e = blockIdx.x * 256 + threadIdx.x;
  int d = dst[e], s = src[e];
  int p = atomicAdd(&cur[d], 1);
  int at = rp[d] + p;
  col[at] = s;
  wgt[at] = dinv[s] * dinv[d];
}

// ---------------- dense matmul: out[N x FOUT] = x[N x FIN] @ W (+bias) ----------------
// WT: W stored [FOUT][FIN] (use W^T), else [FIN][FOUT]. No relu here (agg applies it).

template <int FIN, int FOUT, bool WT, bool BIAS>
__global__ void __launch_bounds__(256) mm_kernel(const float* __restrict__ x,
                                                 const float* __restrict__ w,
                                                 const float* __restrict__ bias,
                                                 float* __restrict__ out) {
  constexpr int VEC = (FOUT >= 32) ? 4 : 1;
  constexpr int TC = FOUT / VEC;   // thread-cols
  constexpr int ROWS = 256 / TC;   // rows per block
  __shared__ float ws[FIN * FOUT];
  __shared__ float xs[ROWS * (FIN + 1)];
  const int tid = threadIdx.x;
  const int r0 = blockIdx.x * ROWS;
  for (int i = tid; i < FIN * FOUT; i += 256) {
    int k = i / FOUT, j = i % FOUT;
    ws[i] = WT ? w[j * FIN + k] : w[i];
  }
  for (int i = tid; i < ROWS * FIN; i += 256) {
    int r = i / FIN, k = i % FIN;
    xs[r * (FIN + 1) + k] = x[(size_t)(r0 + r) * FIN + k];
  }
  __syncthreads();
  const int jc = tid % TC, r = tid / TC;
  float acc[VEC];
#pragma unroll
  for (int v = 0; v < VEC; ++v) acc[v] = 0.0f;
#pragma unroll
  for (int k = 0; k < FIN; ++k) {
    const float xv = xs[r * (FIN + 1) + k];
#pragma unroll
    for (int v = 0; v < VEC; ++v) acc[v] += xv * ws[k * FOUT + jc * VEC + v];
  }
#pragma unroll
  for (int v = 0; v < VEC; ++v) {
    int j = jc * VEC + v;
    out[(size_t)(r0 + r) * FOUT + j] = BIAS ? (acc[v] + bias[j]) : acc[v];
  }
}

// ---------------- GCN aggregation: out = relu(b + dinv^2*t[n] + sum_e w_e t[col_e]) ----------------

template <int F>
__global__ void __launch_bounds__(256) agg_kernel(const float* __restrict__ t,
                                                  const int* __restrict__ rp,
                                                  const int* __restrict__ col,
                                                  const float* __restrict__ wgt,
                                                  const float* __restrict__ dinv,
                                                  const float* __restrict__ bias,
                                                  float* __restrict__ out) {
  constexpr int NPB = 256 / F;
  const int tid = threadIdx.x;
  const int n = blockIdx.x * NPB + tid / F;
  const int f = tid % F;
  const float di = dinv[n];
  float acc = di * di * t[(size_t)n * F + f];
  const int rs = rp[n], re = rp[n + 1];
  for (int e = rs; e < re; ++e) {
    acc += wgt[e] * t[(size_t)col[e] * F + f];
  }
  acc += bias[f];
  out[(size_t)n * F + f] = fmaxf(acc, 0.0f);
}

// ---------------- flash attention, f32, d=32, QB=32, KB=128 ----------------
// qs: QS(d,qi)=qs[d*36+qi]; ks: KS(d,kk)=ks[d*132+kk]
// vs: VS(j,dd)=vs[j*36 + 8*(j>>5) + dd]; ps: PS(qi,j)=ps[qi*140 + j + 4*(j>>5)]

__global__ void __launch_bounds__(256) attn_kernel(const float* __restrict__ q,
                                                   const float* __restrict__ k,
                                                   const float* __restrict__ v,
                                                   float* __restrict__ out) {
  __shared__ float qs[32 * 36];
  __shared__ float ks[32 * 132];
  __shared__ float vs[128 * 36 + 32];
  __shared__ float ps[32 * 140];
  const int tid = threadIdx.x;
  const int q0 = blockIdx.x * 32;
  const int qa = tid >> 5;        // 0..7 : rows q0+qa*4 .. +3
  const int ka = tid & 31;        // phase A: keys ka*4 .. +3
  const int db = (tid >> 2) & 7;  // phase B: dims db*4 .. +3
  const int jb = tid & 3;         // phase B: key quarter

  for (int i = tid; i < 32 * 32; i += 256) {
    int qi = i >> 5, d = i & 31;
    qs[d * 36 + qi] = q[(size_t)(q0 + qi) * 32 + d];
  }

  float m_run[4], l_run[4], o[4][4];
#pragma unroll
  for (int i = 0; i < 4; ++i) {
    m_run[i] = -1e30f;
    l_run[i] = 0.0f;
#pragma unroll
    for (int j = 0; j < 4; ++j) o[i][j] = 0.0f;
  }

  const float SC = 0.17677669529663687f;  // 1/sqrt(32)

  for (int kt = 0; kt < N_NODES; kt += 128) {
    __syncthreads();  // previous iteration's phase B (and Q load) complete
    for (int i = tid; i < 128 * 32; i += 256) {
      int kk = i >> 5, d = i & 31;
      ks[d * 132 + kk] = k[(size_t)(kt + kk) * 32 + d];
      vs[kk * 36 + 8 * (kk >> 5) + d] = v[(size_t)(kt + kk) * 32 + d];
    }
    __syncthreads();

    // ---- phase A: S = Q Kt (4q x 4k per thread) ----
    float s[4][4] = {{0.f, 0.f, 0.f, 0.f},
                     {0.f, 0.f, 0.f, 0.f},
                     {0.f, 0.f, 0.f, 0.f},
                     {0.f, 0.f, 0.f, 0.f}};
#pragma unroll
    for (int d = 0; d < 32; ++d) {
      const float4 qv = *(const float4*)&qs[d * 36 + qa * 4];
      const float4 kv = *(const float4*)&ks[d * 132 + ka * 4];
      s[0][0] += qv.x * kv.x; s[0][1] += qv.x * kv.y; s[0][2] += qv.x * kv.z; s[0][3] += qv.x * kv.w;
      s[1][0] += qv.y * kv.x; s[1][1] += qv.y * kv.y; s[1][2] += qv.y * kv.z; s[1][3] += qv.y * kv.w;
      s[2][0] += qv.z * kv.x; s[2][1] += qv.z * kv.y; s[2][2] += qv.z * kv.z; s[2][3] += qv.z * kv.w;
      s[3][0] += qv.w * kv.x; s[3][1] += qv.w * kv.y; s[3][2] += qv.w * kv.z; s[3][3] += qv.w * kv.w;
    }

    // ---- online softmax (reduce over the 32 ka-lanes = lanes sharing tid>>5) ----
#pragma unroll
    for (int qi = 0; qi < 4; ++qi) {
      float mx = fmaxf(fmaxf(s[qi][0], s[qi][1]), fmaxf(s[qi][2], s[qi][3]));
#pragma unroll
      for (int msk = 16; msk >= 1; msk >>= 1) mx = fmaxf(mx, __shfl_xor(mx, msk, 64));
      mx *= SC;
      const float mnew = fmaxf(m_run[qi], mx);
      const float fct = __expf(m_run[qi] - mnew);
      m_run[qi] = mnew;
      float ls = 0.0f;
#pragma unroll
      for (int kj = 0; kj < 4; ++kj) {
        float p = __expf(s[qi][kj] * SC - mnew);
        s[qi][kj] = p;
        ls += p;
      }
#pragma unroll
      for (int msk = 16; msk >= 1; msk >>= 1) ls += __shfl_xor(ls, msk, 64);
      l_run[qi] = l_run[qi] * fct + ls;
      // store P row (cols 4ka..4ka+3, gapped layout)
      *(float4*)&ps[(qa * 4 + qi) * 140 + ka * 4 + 4 * (ka >> 3)] =
          make_float4(s[qi][0], s[qi][1], s[qi][2], s[qi][3]);
      // rescale O accumulators (same q rows in phase B layout)
#pragma unroll
      for (int di = 0; di < 4; ++di) o[qi][di] *= fct;
    }
    __syncthreads();

    // ---- phase B: O += P V (thread: 4q x 4d over its 32-key quarter) ----
#define PB_ONE(CMP, T2)                                                              \
  do {                                                                               \
    const float4 vv = *(const float4*)&vs[(j + T2) * 36 + 8 * jb + db * 4];          \
    o[0][0] += pv[0].CMP * vv.x; o[0][1] += pv[0].CMP * vv.y;                        \
    o[0][2] += pv[0].CMP * vv.z; o[0][3] += pv[0].CMP * vv.w;                        \
    o[1][0] += pv[1].CMP * vv.x; o[1][1] += pv[1].CMP * vv.y;                        \
    o[1][2] += pv[1].CMP * vv.z; o[1][3] += pv[1].CMP * vv.w;                        \
    o[2][0] += pv[2].CMP * vv.x; o[2][1] += pv[2].CMP * vv.y;                        \
    o[2][2] += pv[2].CMP * vv.z; o[2][3] += pv[2].CMP * vv.w;                        \
    o[3][0] += pv[3].CMP * vv.x; o[3][1] += pv[3].CMP * vv.y;                        \
    o[3][2] += pv[3].CMP * vv.z; o[3][3] += pv[3].CMP * vv.w;                        \
  } while (0)

#pragma unroll
    for (int jj = 0; jj < 32; jj += 4) {
      const int j = jb * 32 + jj;
      const int jcol = j + 4 * jb;  // j + 4*(j>>5)
      float4 pv[4];
#pragma unroll
      for (int qi = 0; qi < 4; ++qi)
        pv[qi] = *(const float4*)&ps[(qa * 4 + qi) * 140 + jcol];
      PB_ONE(x, 0);
      PB_ONE(y, 1);
      PB_ONE(z, 2);
      PB_ONE(w, 3);
    }
#undef PB_ONE
  }

  // reduce over jb quarters (lane bits 0-1)
#pragma unroll
  for (int qi = 0; qi < 4; ++qi)
#pragma unroll
    for (int di = 0; di < 4; ++di) {
      o[qi][di] += __shfl_xor(o[qi][di], 1, 64);
      o[qi][di] += __shfl_xor(o[qi][di], 2, 64);
    }

  // lane writes row (qi == jb), cols db*4..+3
  const float lr = (jb == 0) ? l_run[0] : (jb == 1) ? l_run[1] : (jb == 2) ? l_run[2] : l_run[3];
  const float o0 = (jb == 0) ? o[0][0] : (jb == 1) ? o[1][0] : (jb == 2) ? o[2][0] : o[3][0];
  const float o1 = (jb == 0) ? o[0][1] : (jb == 1) ? o[1][1] : (jb == 2) ? o[2][1] : o[3][1];
  const float o2 = (jb == 0) ? o[0][2] : (jb == 1) ? o[1][2] : (jb == 2) ? o[2][2] : o[3][2];
  const float o3 = (jb == 0) ? o[0][3] : (jb == 1) ? o[1][3] : (jb == 2) ? o[2][3] : o[3][3];
  const float inv = 1.0f / lr;
  *(float4*)&out[(size_t)(q0 + qa * 4 + jb) * 32 + db * 4] =
      make_float4(o0 * inv, o1 * inv, o2 * inv, o3 * inv);
}

// ---------------- launch ----------------

extern "C" void kernel_launch(void* const* d_in, const int* in_sizes, int n_in,
                              void* d_out, int out_size, void* d_ws, size_t ws_size,
                              hipStream_t stream) {
  (void)in_sizes; (void)n_in; (void)out_size; (void)ws_size;
  const int* adj = (const int*)d_in[0];
  const float* feat = (const float*)d_in[1];
  const float* w1 = (const float*)d_in[2];  const float* b1 = (const float*)d_in[3];
  const float* w2 = (const float*)d_in[4];  const float* b2 = (const float*)d_in[5];
  const float* w3 = (const float*)d_in[6];  const float* b3 = (const float*)d_in[7];
  const float* wqkv = (const float*)d_in[8];const float* bqkv = (const float*)d_in[9];
  const float* wo = (const float*)d_in[10]; const float* bo = (const float*)d_in[11];
  const float* w4 = (const float*)d_in[12]; const float* b4 = (const float*)d_in[13];
  const float* w5a = (const float*)d_in[14];const float* b5a = (const float*)d_in[15];
  const float* w6a = (const float*)d_in[16];const float* b6a = (const float*)d_in[17];
  const float* w7a = (const float*)d_in[18];const float* b7a = (const float*)d_in[19];
  const float* w5f = (const float*)d_in[20];const float* b5f = (const float*)d_in[21];
  const float* w6f = (const float*)d_in[22];const float* b6f = (const float*)d_in[23];
  const float* w7f = (const float*)d_in[24];const float* b7f = (const float*)d_in[25];
  float* outp = (float*)d_out;

  float* wsf = (float*)d_ws;
  int* wsi = (int*)d_ws;
  int* cnt = wsi;                 // 8192
  int* cur = wsi + 8192;          // 8192
  int* rp = wsi + 16384;          // 8193
  float* dinv = wsf + 24832;      // 8192
  float* wgt = wsf + 33024;       // 262144
  int* col = wsi + 295168;        // 262144
  float* T = wsf + 557312;        // 8192*128
  float* B0 = wsf + 1605888;      // 8192*64
  float* B1 = wsf + 2130176;      // 8192*32
  float* B2 = wsf + 2392320;      // 8192*64

  const int* src = adj;
  const int* dst = adj + N_EDGES;

  hipMemsetAsync(cnt, 0, 2 * N_NODES * sizeof(int), stream);  // cnt + cur
  count_kernel<<<N_EDGES / 256, 256, 0, stream>>>(dst, cnt);
  scan_kernel<<<1, 1024, 0, stream>>>(cnt, rp, dinv);
  fill_kernel<<<N_EDGES / 256, 256, 0, stream>>>(src, dst, rp, dinv, cur, col, wgt);

  // gcn1: 128 -> 64
  mm_kernel<128, 64, false, false><<<N_NODES / 16, 256, 0, stream>>>(feat, w1, nullptr, T);
  agg_kernel<64><<<N_NODES / 4, 256, 0, stream>>>(T, rp, col, wgt, dinv, b1, B0);
  // gcn2: 64 -> 32
  mm_kernel<64, 32, false, false><<<N_NODES / 32, 256, 0, stream>>>(B0, w2, nullptr, T);
  agg_kernel<32><<<N_NODES / 8, 256, 0, stream>>>(T, rp, col, wgt, dinv, b2, B1);
  // gcn3: 32 -> 32
  mm_kernel<32, 32, false, false><<<N_NODES / 32, 256, 0, stream>>>(B1, w3, nullptr, T);
  agg_kernel<32><<<N_NODES / 8, 256, 0, stream>>>(T, rp, col, wgt, dinv, b3, B0);  // h3 in B0

  // qkv (x @ Wqkv^T + b), slices of wqkv [96][32]
  mm_kernel<32, 32, true, true><<<N_NODES / 32, 256, 0, stream>>>(B0, wqkv, bqkv, T);
  mm_kernel<32, 32, true, true><<<N_NODES / 32, 256, 0, stream>>>(B0, wqkv + 1024, bqkv + 32, T + 262144);
  mm_kernel<32, 32, true, true><<<N_NODES / 32, 256, 0, stream>>>(B0, wqkv + 2048, bqkv + 64, T + 524288);
  attn_kernel<<<N_NODES / 32, 256, 0, stream>>>(T, T + 262144, T + 524288, B1);
  mm_kernel<32, 32, true, true><<<N_NODES / 32, 256, 0, stream>>>(B1, wo, bo, B2);  // h_attn in B2

  // gcn4: 32 -> 32
  mm_kernel<32, 32, false, false><<<N_NODES / 32, 256, 0, stream>>>(B2, w4, nullptr, T);
  agg_kernel<32><<<N_NODES / 8, 256, 0, stream>>>(T, rp, col, wgt, dinv, b4, B0);  // h4 in B0

  // da head: 32->32->64->2
  mm_kernel<32, 32, false, false><<<N_NODES / 32, 256, 0, stream>>>(B0, w5a, nullptr, T);
  agg_kernel<32><<<N_NODES / 8, 256, 0, stream>>>(T, rp, col, wgt, dinv, b5a, B1);
  mm_kernel<32, 64, false, false><<<N_NODES / 16, 256, 0, stream>>>(B1, w6a, nullptr, T);
  agg_kernel<64><<<N_NODES / 4, 256, 0, stream>>>(T, rp, col, wgt, dinv, b6a, B2);
  mm_kernel<64, 2, false, false><<<N_NODES / 128, 256, 0, stream>>>(B2, w7a, nullptr, T);
  agg_kernel<2><<<N_NODES / 128, 256, 0, stream>>>(T, rp, col, wgt, dinv, b7a, outp);

  // df head: 32->32->64->128
  mm_kernel<32, 32, false, false><<<N_NODES / 32, 256, 0, stream>>>(B0, w5f, nullptr, T);
  agg_kernel<32><<<N_NODES / 8, 256, 0, stream>>>(T, rp, col, wgt, dinv, b5f, B1);
  mm_kernel<32, 64, false, false><<<N_NODES / 16, 256, 0, stream>>>(B1, w6f, nullptr, T);
  agg_kernel<64><<<N_NODES / 4, 256, 0, stream>>>(T, rp, col, wgt, dinv, b6f, B2);
  mm_kernel<64, 128, false, false><<<N_NODES / 8, 256, 0, stream>>>(B2, w7f, nullptr, T);
  agg_kernel<128><<<N_NODES / 2, 256, 0, stream>>>(T, rp, col, wgt, dinv, b7f, outp + 16384);
}

// Round 2
// 456.300 us; speedup vs baseline: 1.4604x; 1.4604x over previous
//
#include <hip/hip_runtime.h>

#define N_NODES 8192
#define N_EDGES 262144

typedef __attribute__((ext_vector_type(8))) short short8v;
typedef __attribute__((ext_vector_type(4))) short short4v;
typedef __attribute__((ext_vector_type(4))) float f32x4;

union U8 { short8v s8; short4v h[2]; unsigned u[4]; };

__device__ inline unsigned short f2bf(float f) {
  union { float f; unsigned u; } v; v.f = f;
  unsigned r = v.u + 0x7fffu + ((v.u >> 16) & 1u);
  return (unsigned short)(r >> 16);
}
__device__ inline float bf2f(unsigned short b) {
  union { unsigned u; float f; } v; v.u = ((unsigned)b) << 16;
  return v.f;
}
__device__ inline unsigned cvt_pk_bf16(float lo, float hi) {
  unsigned r;
  asm("v_cvt_pk_bf16_f32 %0, %1, %2" : "=v"(r) : "v"(lo), "v"(hi));
  return r;
}

// ---------------- CSR build ----------------

__global__ void __launch_bounds__(256) count_kernel(const int* __restrict__ dst,
                                                    int* __restrict__ cnt) {
  int e = blockIdx.x * 256 + threadIdx.x;
  atomicAdd(&cnt[dst[e]], 1);
}

__global__ void __launch_bounds__(1024) scan_kernel(const int* __restrict__ cnt,
                                                    int* __restrict__ rp,
                                                    float* __restrict__ dinv) {
  __shared__ int sums[1024];
  const int t = threadIdx.x;
  const int base = t * 8;
  int c[8];
  int s = 0;
#pragma unroll
  for (int i = 0; i < 8; ++i) { c[i] = cnt[base + i]; s += c[i]; }
  sums[t] = s;
  __syncthreads();
  for (int off = 1; off < 1024; off <<= 1) {
    int v = (t >= off) ? sums[t - off] : 0;
    __syncthreads();
    sums[t] += v;
    __syncthreads();
  }
  int run = (t == 0) ? 0 : sums[t - 1];
#pragma unroll
  for (int i = 0; i < 8; ++i) {
    rp[base + i] = run;
    run += c[i];
    dinv[base + i] = rsqrtf((float)(c[i] + 1));
  }
  if (t == 1023) rp[N_NODES] = run;
}

__global__ void __launch_bounds__(256) fill_kernel(const int* __restrict__ src,
                                                   const int* __restrict__ dst,
                                                   const int* __restrict__ rp,
                                                   const float* __restrict__ dinv,
                                                   int* __restrict__ cur,
                                                   int* __restrict__ col,
                                                   float* __restrict__ wgt) {
  int e = blockIdx.x * 256 + threadIdx.x;
  int d = dst[e], s = src[e];
  int p = atomicAdd(&cur[d], 1);
  int at = rp[d] + p;
  col[at] = s;
  wgt[at] = dinv[s] * dinv[d];
}

// ---------------- dense matmul ----------------

template <int FIN, int FOUT, bool WT, bool BIAS>
__global__ void __launch_bounds__(256) mm_kernel(const float* __restrict__ x,
                                                 const float* __restrict__ w,
                                                 const float* __restrict__ bias,
                                                 float* __restrict__ out) {
  constexpr int VEC = (FOUT >= 32) ? 4 : 1;
  constexpr int TC = FOUT / VEC;
  constexpr int ROWS = 256 / TC;
  __shared__ float ws[FIN * FOUT];
  __shared__ float xs[ROWS * (FIN + 1)];
  const int tid = threadIdx.x;
  const int r0 = blockIdx.x * ROWS;
  for (int i = tid; i < FIN * FOUT; i += 256) {
    int k = i / FOUT, j = i % FOUT;
    ws[i] = WT ? w[j * FIN + k] : w[i];
  }
  for (int i = tid; i < ROWS * FIN; i += 256) {
    int r = i / FIN, k = i % FIN;
    xs[r * (FIN + 1) + k] = x[(size_t)(r0 + r) * FIN + k];
  }
  __syncthreads();
  const int jc = tid % TC, r = tid / TC;
  float acc[VEC];
#pragma unroll
  for (int v = 0; v < VEC; ++v) acc[v] = 0.0f;
#pragma unroll
  for (int k = 0; k < FIN; ++k) {
    const float xv = xs[r * (FIN + 1) + k];
#pragma unroll
    for (int v = 0; v < VEC; ++v) acc[v] += xv * ws[k * FOUT + jc * VEC + v];
  }
#pragma unroll
  for (int v = 0; v < VEC; ++v) {
    int j = jc * VEC + v;
    out[(size_t)(r0 + r) * FOUT + j] = BIAS ? (acc[v] + bias[j]) : acc[v];
  }
}

// ---------------- GCN aggregation ----------------

template <int F>
__global__ void __launch_bounds__(256) agg_kernel(const float* __restrict__ t,
                                                  const int* __restrict__ rp,
                                                  const int* __restrict__ col,
                                                  const float* __restrict__ wgt,
                                                  const float* __restrict__ dinv,
                                                  const float* __restrict__ bias,
                                                  float* __restrict__ out) {
  constexpr int NPB = 256 / F;
  const int tid = threadIdx.x;
  const int n = blockIdx.x * NPB + tid / F;
  const int f = tid % F;
  const float di = dinv[n];
  float acc = di * di * t[(size_t)n * F + f];
  const int rs = rp[n], re = rp[n + 1];
  for (int e = rs; e < re; ++e) {
    acc += wgt[e] * t[(size_t)col[e] * F + f];
  }
  acc += bias[f];
  out[(size_t)n * F + f] = fmaxf(acc, 0.0f);
}

// ---------------- fused QKV projection -> bf16 hi/lo buffers ----------------
// Q scaled by log2(e)/sqrt(32) (folds softmax scale + exp2 conversion).
// V stored transposed [32][8192] for the PV A-fragment.

__global__ void __launch_bounds__(256) qkv_kernel(const float* __restrict__ x,
                                                  const float* __restrict__ wqkv,
                                                  const float* __restrict__ bqkv,
                                                  unsigned short* __restrict__ Qh,
                                                  unsigned short* __restrict__ Ql,
                                                  unsigned short* __restrict__ Kh,
                                                  unsigned short* __restrict__ Kl,
                                                  unsigned short* __restrict__ VTh,
                                                  unsigned short* __restrict__ VTl) {
  __shared__ float wls[96 * 33];
  __shared__ float xs[8 * 33];
  const int tid = threadIdx.x;
  const int r = tid >> 5, j = tid & 31;
  const int row = blockIdx.x * 8 + r;
  for (int i = tid; i < 96 * 32; i += 256) wls[(i >> 5) * 33 + (i & 31)] = wqkv[i];
  xs[(tid >> 5) * 33 + (tid & 31)] = x[(size_t)(blockIdx.x * 8 + (tid >> 5)) * 32 + (tid & 31)];
  __syncthreads();
  float aq = bqkv[j], ak = bqkv[32 + j], av = bqkv[64 + j];
#pragma unroll
  for (int k = 0; k < 32; ++k) {
    const float xv = xs[r * 33 + k];
    aq += xv * wls[j * 33 + k];
    ak += xv * wls[(32 + j) * 33 + k];
    av += xv * wls[(64 + j) * 33 + k];
  }
  const float QSCALE = 1.4426950408889634f * 0.17677669529663687f;  // log2e/sqrt(32)
  aq *= QSCALE;
  unsigned short qh = f2bf(aq);
  unsigned short ql = f2bf(aq - bf2f(qh));
  unsigned short kh = f2bf(ak);
  unsigned short kl = f2bf(ak - bf2f(kh));
  unsigned short vh = f2bf(av);
  unsigned short vl = f2bf(av - bf2f(vh));
  Qh[row * 32 + j] = qh;  Ql[row * 32 + j] = ql;
  Kh[row * 32 + j] = kh;  Kl[row * 32 + j] = kl;
  VTh[j * N_NODES + row] = vh;  VTl[j * N_NODES + row] = vl;
}

// ---------------- MFMA flash attention (bf16x3), swapped-QK^T, KSPLIT=4 ----------------
// Per wave: 16 q-rows, 2048-key range. S^T = K*Q via 16x16x32 (d=32 in one mfma).
// C/D layout: col=lane&15 (q), row=4*(lane>>4)+reg (k or d) -> softmax fully lane-local per q.
// PV: A = V^T frag (kappa-slot 8g+j -> keys t+4g+j / t+16+4g+j-4), B = P frag (lane-local).

__global__ void __launch_bounds__(256) attn_mfma_kernel(
    const unsigned short* __restrict__ Qh, const unsigned short* __restrict__ Ql,
    const unsigned short* __restrict__ Kh, const unsigned short* __restrict__ Kl,
    const unsigned short* __restrict__ VTh, const unsigned short* __restrict__ VTl,
    float* __restrict__ part) {
  const int tid = threadIdx.x;
  const int wid = tid >> 6;
  const int lane = tid & 63;
  const int g = lane >> 4;
  const int li = lane & 15;
  const int qtile = blockIdx.x * 4 + wid;
  const int q0 = qtile * 16;
  const int kbeg = blockIdx.y * 2048;

  const short8v qfh = *(const short8v*)&Qh[(q0 + li) * 32 + 8 * g];
  const short8v qfl = *(const short8v*)&Ql[(q0 + li) * 32 + 8 * g];

  const int koff = li * 32 + 8 * g;
  const unsigned short* pVhA = VTh + (size_t)li * N_NODES;
  const unsigned short* pVhB = VTh + (size_t)(16 + li) * N_NODES;
  const unsigned short* pVlA = VTl + (size_t)li * N_NODES;
  const unsigned short* pVlB = VTl + (size_t)(16 + li) * N_NODES;

  f32x4 oA = {0.f, 0.f, 0.f, 0.f};
  f32x4 oB = {0.f, 0.f, 0.f, 0.f};
  float m = -1e30f, l = 0.f;

  for (int t = kbeg; t < kbeg + 2048; t += 32) {
    const short8v k0h = *(const short8v*)&Kh[t * 32 + koff];
    const short8v k0l = *(const short8v*)&Kl[t * 32 + koff];
    const short8v k1h = *(const short8v*)&Kh[(t + 16) * 32 + koff];
    const short8v k1l = *(const short8v*)&Kl[(t + 16) * 32 + koff];

    f32x4 s0 = {0.f, 0.f, 0.f, 0.f}, s1 = {0.f, 0.f, 0.f, 0.f};
    s0 = __builtin_amdgcn_mfma_f32_16x16x32_bf16(k0h, qfh, s0, 0, 0, 0);
    s0 = __builtin_amdgcn_mfma_f32_16x16x32_bf16(k0l, qfh, s0, 0, 0, 0);
    s0 = __builtin_amdgcn_mfma_f32_16x16x32_bf16(k0h, qfl, s0, 0, 0, 0);
    s1 = __builtin_amdgcn_mfma_f32_16x16x32_bf16(k1h, qfh, s1, 0, 0, 0);
    s1 = __builtin_amdgcn_mfma_f32_16x16x32_bf16(k1l, qfh, s1, 0, 0, 0);
    s1 = __builtin_amdgcn_mfma_f32_16x16x32_bf16(k1h, qfl, s1, 0, 0, 0);

    // online softmax (per-lane q; reduce over g-groups via xor 16,32)
    float mx = fmaxf(fmaxf(fmaxf(s0[0], s0[1]), fmaxf(s0[2], s0[3])),
                     fmaxf(fmaxf(s1[0], s1[1]), fmaxf(s1[2], s1[3])));
    mx = fmaxf(mx, __shfl_xor(mx, 16, 64));
    mx = fmaxf(mx, __shfl_xor(mx, 32, 64));
    const float mnew = fmaxf(m, mx);
    const float fct = exp2f(m - mnew);
    m = mnew;
    const float p0 = exp2f(s0[0] - mnew), p1 = exp2f(s0[1] - mnew);
    const float p2 = exp2f(s0[2] - mnew), p3 = exp2f(s0[3] - mnew);
    const float p4 = exp2f(s1[0] - mnew), p5 = exp2f(s1[1] - mnew);
    const float p6 = exp2f(s1[2] - mnew), p7 = exp2f(s1[3] - mnew);
    float ls = ((p0 + p1) + (p2 + p3)) + ((p4 + p5) + (p6 + p7));
    ls += __shfl_xor(ls, 16, 64);
    ls += __shfl_xor(ls, 32, 64);
    l = l * fct + ls;
    oA *= fct;
    oB *= fct;

    // P fragments (hi + compensation lo)
    U8 ph, pl;
    ph.u[0] = cvt_pk_bf16(p0, p1);
    ph.u[1] = cvt_pk_bf16(p2, p3);
    ph.u[2] = cvt_pk_bf16(p4, p5);
    ph.u[3] = cvt_pk_bf16(p6, p7);
    const float h0 = __uint_as_float(ph.u[0] << 16), h1 = __uint_as_float(ph.u[0] & 0xffff0000u);
    const float h2 = __uint_as_float(ph.u[1] << 16), h3 = __uint_as_float(ph.u[1] & 0xffff0000u);
    const float h4 = __uint_as_float(ph.u[2] << 16), h5 = __uint_as_float(ph.u[2] & 0xffff0000u);
    const float h6 = __uint_as_float(ph.u[3] << 16), h7 = __uint_as_float(ph.u[3] & 0xffff0000u);
    pl.u[0] = cvt_pk_bf16(p0 - h0, p1 - h1);
    pl.u[1] = cvt_pk_bf16(p2 - h2, p3 - h3);
    pl.u[2] = cvt_pk_bf16(p4 - h4, p5 - h5);
    pl.u[3] = cvt_pk_bf16(p6 - h6, p7 - h7);

    // V fragments
    U8 vhA, vlA, vhB, vlB;
    vhA.h[0] = *(const short4v*)&pVhA[t + 4 * g];
    vhA.h[1] = *(const short4v*)&pVhA[t + 16 + 4 * g];
    vlA.h[0] = *(const short4v*)&pVlA[t + 4 * g];
    vlA.h[1] = *(const short4v*)&pVlA[t + 16 + 4 * g];
    vhB.h[0] = *(const short4v*)&pVhB[t + 4 * g];
    vhB.h[1] = *(const short4v*)&pVhB[t + 16 + 4 * g];
    vlB.h[0] = *(const short4v*)&pVlB[t + 4 * g];
    vlB.h[1] = *(const short4v*)&pVlB[t + 16 + 4 * g];

    oA = __builtin_amdgcn_mfma_f32_16x16x32_bf16(vhA.s8, ph.s8, oA, 0, 0, 0);
    oA = __builtin_amdgcn_mfma_f32_16x16x32_bf16(vlA.s8, ph.s8, oA, 0, 0, 0);
    oA = __builtin_amdgcn_mfma_f32_16x16x32_bf16(vhA.s8, pl.s8, oA, 0, 0, 0);
    oB = __builtin_amdgcn_mfma_f32_16x16x32_bf16(vhB.s8, ph.s8, oB, 0, 0, 0);
    oB = __builtin_amdgcn_mfma_f32_16x16x32_bf16(vlB.s8, ph.s8, oB, 0, 0, 0);
    oB = __builtin_amdgcn_mfma_f32_16x16x32_bf16(vhB.s8, pl.s8, oB, 0, 0, 0);
  }

  const int base = (qtile * 4 + blockIdx.y) * 544;
#pragma unroll
  for (int r = 0; r < 4; ++r) {
    part[base + (4 * g + r) * 16 + li] = oA[r];
    part[base + (16 + 4 * g + r) * 16 + li] = oB[r];
  }
  if (g == 0) {
    part[base + 512 + li] = m;
    part[base + 528 + li] = l;
  }
}

// ---------------- combine partials: out[q][d] = (sum_s w_s O_s) / (sum_s w_s l_s) ----------------

__global__ void __launch_bounds__(64) attn_combine(const float* __restrict__ part,
                                                   float* __restrict__ out) {
  const int qt = blockIdx.x;
  const int lane = threadIdx.x;
  const int q = lane & 15;
  const int jg = lane >> 4;
  float ms[4], lsv[4];
#pragma unroll
  for (int s = 0; s < 4; ++s) {
    ms[s] = part[(qt * 4 + s) * 544 + 512 + q];
    lsv[s] = part[(qt * 4 + s) * 544 + 528 + q];
  }
  const float M = fmaxf(fmaxf(ms[0], ms[1]), fmaxf(ms[2], ms[3]));
  float w[4], L = 0.f;
#pragma unroll
  for (int s = 0; s < 4; ++s) {
    w[s] = exp2f(ms[s] - M);
    L += w[s] * lsv[s];
  }
  const float invL = 1.0f / L;
#pragma unroll
  for (int kk = 0; kk < 8; ++kk) {
    const int d = jg * 8 + kk;
    float acc = 0.f;
#pragma unroll
    for (int s = 0; s < 4; ++s) acc += w[s] * part[(qt * 4 + s) * 544 + d * 16 + q];
    out[(size_t)(qt * 16 + q) * 32 + d] = acc * invL;
  }
}

// ---------------- launch ----------------

extern "C" void kernel_launch(void* const* d_in, const int* in_sizes, int n_in,
                              void* d_out, int out_size, void* d_ws, size_t ws_size,
                              hipStream_t stream) {
  (void)in_sizes; (void)n_in; (void)out_size; (void)ws_size;
  const int* adj = (const int*)d_in[0];
  const float* feat = (const float*)d_in[1];
  const float* w1 = (const float*)d_in[2];  const float* b1 = (const float*)d_in[3];
  const float* w2 = (const float*)d_in[4];  const float* b2 = (const float*)d_in[5];
  const float* w3 = (const float*)d_in[6];  const float* b3 = (const float*)d_in[7];
  const float* wqkv = (const float*)d_in[8];const float* bqkv = (const float*)d_in[9];
  const float* wo = (const float*)d_in[10]; const float* bo = (const float*)d_in[11];
  const float* w4 = (const float*)d_in[12]; const float* b4 = (const float*)d_in[13];
  const float* w5a = (const float*)d_in[14];const float* b5a = (const float*)d_in[15];
  const float* w6a = (const float*)d_in[16];const float* b6a = (const float*)d_in[17];
  const float* w7a = (const float*)d_in[18];const float* b7a = (const float*)d_in[19];
  const float* w5f = (const float*)d_in[20];const float* b5f = (const float*)d_in[21];
  const float* w6f = (const float*)d_in[22];const float* b6f = (const float*)d_in[23];
  const float* w7f = (const float*)d_in[24];const float* b7f = (const float*)d_in[25];
  float* outp = (float*)d_out;

  float* wsf = (float*)d_ws;
  int* wsi = (int*)d_ws;
  int* cnt = wsi;                 // 8192
  int* cur = wsi + 8192;          // 8192
  int* rp = wsi + 16384;          // 8193
  float* dinv = wsf + 24832;      // 8192
  float* wgt = wsf + 33024;       // 262144
  int* col = wsi + 295168;        // 262144
  float* T = wsf + 557312;        // 8192*128
  float* B0 = wsf + 1605888;      // 8192*64
  float* B1 = wsf + 2130176;      // 8192*32
  float* B2 = wsf + 2392320;      // 8192*64  (end 2916608)
  // bf16 attention buffers (131072 ushorts = 65536 f32 each)
  unsigned short* Qh = (unsigned short*)(wsf + 2916608);
  unsigned short* Ql = Qh + 131072;
  unsigned short* Kh = Ql + 131072;
  unsigned short* Kl = Kh + 131072;
  unsigned short* VTh = Kl + 131072;
  unsigned short* VTl = VTh + 131072;
  // attention partials (512 qtiles x 4 splits x 544 f32) reuse T (+ dead B0 head)
  float* part = T;

  const int* src = adj;
  const int* dst = adj + N_EDGES;

  hipMemsetAsync(cnt, 0, 2 * N_NODES * sizeof(int), stream);  // cnt + cur
  count_kernel<<<N_EDGES / 256, 256, 0, stream>>>(dst, cnt);
  scan_kernel<<<1, 1024, 0, stream>>>(cnt, rp, dinv);
  fill_kernel<<<N_EDGES / 256, 256, 0, stream>>>(src, dst, rp, dinv, cur, col, wgt);

  // gcn1: 128 -> 64
  mm_kernel<128, 64, false, false><<<N_NODES / 16, 256, 0, stream>>>(feat, w1, nullptr, T);
  agg_kernel<64><<<N_NODES / 4, 256, 0, stream>>>(T, rp, col, wgt, dinv, b1, B0);
  // gcn2: 64 -> 32
  mm_kernel<64, 32, false, false><<<N_NODES / 32, 256, 0, stream>>>(B0, w2, nullptr, T);
  agg_kernel<32><<<N_NODES / 8, 256, 0, stream>>>(T, rp, col, wgt, dinv, b2, B1);
  // gcn3: 32 -> 32
  mm_kernel<32, 32, false, false><<<N_NODES / 32, 256, 0, stream>>>(B1, w3, nullptr, T);
  agg_kernel<32><<<N_NODES / 8, 256, 0, stream>>>(T, rp, col, wgt, dinv, b3, B0);  // h3 in B0

  // attention: fused qkv -> bf16 hi/lo, MFMA flash with KSPLIT=4, combine
  qkv_kernel<<<N_NODES / 8, 256, 0, stream>>>(B0, wqkv, bqkv, Qh, Ql, Kh, Kl, VTh, VTl);
  {
    dim3 grid(128, 4);
    attn_mfma_kernel<<<grid, 256, 0, stream>>>(Qh, Ql, Kh, Kl, VTh, VTl, part);
  }
  attn_combine<<<512, 64, 0, stream>>>(part, B1);
  mm_kernel<32, 32, true, true><<<N_NODES / 32, 256, 0, stream>>>(B1, wo, bo, B2);  // h_attn in B2

  // gcn4: 32 -> 32
  mm_kernel<32, 32, false, false><<<N_NODES / 32, 256, 0, stream>>>(B2, w4, nullptr, T);
  agg_kernel<32><<<N_NODES / 8, 256, 0, stream>>>(T, rp, col, wgt, dinv, b4, B0);  // h4 in B0

  // da head: 32->32->64->2
  mm_kernel<32, 32, false, false><<<N_NODES / 32, 256, 0, stream>>>(B0, w5a, nullptr, T);
  agg_kernel<32><<<N_NODES / 8, 256, 0, stream>>>(T, rp, col, wgt, dinv, b5a, B1);
  mm_kernel<32, 64, false, false><<<N_NODES / 16, 256, 0, stream>>>(B1, w6a, nullptr, T);
  agg_kernel<64><<<N_NODES / 4, 256, 0, stream>>>(T, rp, col, wgt, dinv, b6a, B2);
  mm_kernel<64, 2, false, false><<<N_NODES / 128, 256, 0, stream>>>(B2, w7a, nullptr, T);
  agg_kernel<2><<<N_NODES / 128, 256, 0, stream>>>(T, rp, col, wgt, dinv, b7a, outp);

  // df head: 32->32->64->128
  mm_kernel<32, 32, false, false><<<N_NODES / 32, 256, 0, stream>>>(B0, w5f, nullptr, T);
  agg_kernel<32><<<N_NODES / 8, 256, 0, stream>>>(T, rp, col, wgt, dinv, b5f, B1);
  mm_kernel<32, 64, false, false><<<N_NODES / 16, 256, 0, stream>>>(B1, w6f, nullptr, T);
  agg_kernel<64><<<N_NODES / 4, 256, 0, stream>>>(T, rp, col, wgt, dinv, b6f, B2);
  mm_kernel<64, 128, false, false><<<N_NODES / 8, 256, 0, stream>>>(B2, w7f, nullptr, T);
  agg_kernel<128><<<N_NODES / 2, 256, 0, stream>>>(T, rp, col, wgt, dinv, b7f, outp + 16384);
}

// Round 3
// 341.023 us; speedup vs baseline: 1.9540x; 1.3380x over previous
//
#include <hip/hip_runtime.h>

#define N_NODES 8192
#define N_EDGES 262144

typedef __attribute__((ext_vector_type(8))) short short8v;
typedef __attribute__((ext_vector_type(4))) short short4v;
typedef __attribute__((ext_vector_type(4))) float f32x4;

union U8 { short8v s8; short4v h[2]; unsigned u[4]; };

__device__ inline unsigned short f2bf(float f) {
  union { float f; unsigned u; } v; v.f = f;
  unsigned r = v.u + 0x7fffu + ((v.u >> 16) & 1u);
  return (unsigned short)(r >> 16);
}
__device__ inline float bf2f(unsigned short b) {
  union { unsigned u; float f; } v; v.u = ((unsigned)b) << 16;
  return v.f;
}
__device__ inline unsigned cvt_pk_bf16(float lo, float hi) {
  unsigned r;
  asm("v_cvt_pk_bf16_f32 %0, %1, %2" : "=v"(r) : "v"(lo), "v"(hi));
  return r;
}

// ---------------- CSR build ----------------

__global__ void __launch_bounds__(256) count_kernel(const int* __restrict__ dst,
                                                    int* __restrict__ cnt) {
  int e = blockIdx.x * 256 + threadIdx.x;
  atomicAdd(&cnt[dst[e]], 1);
}

__global__ void __launch_bounds__(1024) scan_kernel(const int* __restrict__ cnt,
                                                    int* __restrict__ rp,
                                                    float* __restrict__ dinv) {
  __shared__ int sums[1024];
  const int t = threadIdx.x;
  const int base = t * 8;
  int c[8];
  int s = 0;
#pragma unroll
  for (int i = 0; i < 8; ++i) { c[i] = cnt[base + i]; s += c[i]; }
  sums[t] = s;
  __syncthreads();
  for (int off = 1; off < 1024; off <<= 1) {
    int v = (t >= off) ? sums[t - off] : 0;
    __syncthreads();
    sums[t] += v;
    __syncthreads();
  }
  int run = (t == 0) ? 0 : sums[t - 1];
#pragma unroll
  for (int i = 0; i < 8; ++i) {
    rp[base + i] = run;
    run += c[i];
    dinv[base + i] = rsqrtf((float)(c[i] + 1));
  }
  if (t == 1023) rp[N_NODES] = run;
}

__global__ void __launch_bounds__(256) fill_kernel(const int* __restrict__ src,
                                                   const int* __restrict__ dst,
                                                   const int* __restrict__ rp,
                                                   const float* __restrict__ dinv,
                                                   int* __restrict__ cur,
                                                   int* __restrict__ col,
                                                   float* __restrict__ wgt) {
  int e = blockIdx.x * 256 + threadIdx.x;
  int d = dst[e], s = src[e];
  int p = atomicAdd(&cur[d], 1);
  int at = rp[d] + p;
  col[at] = s;
  wgt[at] = dinv[s] * dinv[d];
}

// ---------------- dense matmul ----------------

template <int FIN, int FOUT, bool WT, bool BIAS>
__global__ void __launch_bounds__(256) mm_kernel(const float* __restrict__ x,
                                                 const float* __restrict__ w,
                                                 const float* __restrict__ bias,
                                                 float* __restrict__ out) {
  constexpr int VEC = (FOUT >= 32) ? 4 : 1;
  constexpr int TC = FOUT / VEC;
  constexpr int ROWS = 256 / TC;
  __shared__ float ws[FIN * FOUT];
  __shared__ float xs[ROWS * (FIN + 1)];
  const int tid = threadIdx.x;
  const int r0 = blockIdx.x * ROWS;
  for (int i = tid; i < FIN * FOUT; i += 256) {
    int k = i / FOUT, j = i % FOUT;
    ws[i] = WT ? w[j * FIN + k] : w[i];
  }
  for (int i = tid; i < ROWS * FIN; i += 256) {
    int r = i / FIN, k = i % FIN;
    xs[r * (FIN + 1) + k] = x[(size_t)(r0 + r) * FIN + k];
  }
  __syncthreads();
  const int jc = tid % TC, r = tid / TC;
  float acc[VEC];
#pragma unroll
  for (int v = 0; v < VEC; ++v) acc[v] = 0.0f;
#pragma unroll
  for (int k = 0; k < FIN; ++k) {
    const float xv = xs[r * (FIN + 1) + k];
#pragma unroll
    for (int v = 0; v < VEC; ++v) acc[v] += xv * ws[k * FOUT + jc * VEC + v];
  }
#pragma unroll
  for (int v = 0; v < VEC; ++v) {
    int j = jc * VEC + v;
    out[(size_t)(r0 + r) * FOUT + j] = BIAS ? (acc[v] + bias[j]) : acc[v];
  }
}

// ---------------- GCN aggregation: one wave per node, float4, multi-edge ILP ----------------
// F in {32,64,128}. TPN = F/4 lanes cover the features; EPI = 64/TPN edges in flight.

template <int F>
__global__ void __launch_bounds__(256) aggv_kernel(const float* __restrict__ t,
                                                   const int* __restrict__ rp,
                                                   const int* __restrict__ col,
                                                   const float* __restrict__ wgt,
                                                   const float* __restrict__ dinv,
                                                   const float* __restrict__ bias,
                                                   float* __restrict__ out) {
  constexpr int TPN = F / 4;
  constexpr int EPI = 64 / TPN;
  const int tid = threadIdx.x;
  const int wv = tid >> 6;
  const int lane = tid & 63;
  const int n = blockIdx.x * 4 + wv;
  const int eo = lane / TPN;
  const int fq = lane % TPN;
  const float di = dinv[n];
  const int rs = rp[n], re = rp[n + 1];
  f32x4 acc = {0.f, 0.f, 0.f, 0.f};
  if (eo == 0) {
    const f32x4 tv = *(const f32x4*)&t[(size_t)n * F + fq * 4];
    acc = di * di * tv;
  }
  for (int e = rs + eo; e < re; e += EPI) {
    const int c = col[e];
    const float w = wgt[e];
    const f32x4 tv = *(const f32x4*)&t[(size_t)c * F + fq * 4];
    acc += w * tv;
  }
#pragma unroll
  for (int off = TPN; off < 64; off <<= 1) {
    acc[0] += __shfl_xor(acc[0], off, 64);
    acc[1] += __shfl_xor(acc[1], off, 64);
    acc[2] += __shfl_xor(acc[2], off, 64);
    acc[3] += __shfl_xor(acc[3], off, 64);
  }
  if (eo == 0) {
    const f32x4 bv = *(const f32x4*)&bias[fq * 4];
    f32x4 r = acc + bv;
    r[0] = fmaxf(r[0], 0.f); r[1] = fmaxf(r[1], 0.f);
    r[2] = fmaxf(r[2], 0.f); r[3] = fmaxf(r[3], 0.f);
    *(f32x4*)&out[(size_t)n * F + fq * 4] = r;
  }
}

// F=2 tail layer (da head output)
template <int F>
__global__ void __launch_bounds__(256) agg_kernel(const float* __restrict__ t,
                                                  const int* __restrict__ rp,
                                                  const int* __restrict__ col,
                                                  const float* __restrict__ wgt,
                                                  const float* __restrict__ dinv,
                                                  const float* __restrict__ bias,
                                                  float* __restrict__ out) {
  constexpr int NPB = 256 / F;
  const int tid = threadIdx.x;
  const int n = blockIdx.x * NPB + tid / F;
  const int f = tid % F;
  const float di = dinv[n];
  float acc = di * di * t[(size_t)n * F + f];
  const int rs = rp[n], re = rp[n + 1];
  for (int e = rs; e < re; ++e) {
    acc += wgt[e] * t[(size_t)col[e] * F + f];
  }
  acc += bias[f];
  out[(size_t)n * F + f] = fmaxf(acc, 0.0f);
}

// ---------------- fused QKV projection -> bf16 hi/lo buffers ----------------

__global__ void __launch_bounds__(256) qkv_kernel(const float* __restrict__ x,
                                                  const float* __restrict__ wqkv,
                                                  const float* __restrict__ bqkv,
                                                  unsigned short* __restrict__ Qh,
                                                  unsigned short* __restrict__ Ql,
                                                  unsigned short* __restrict__ Kh,
                                                  unsigned short* __restrict__ Kl,
                                                  unsigned short* __restrict__ VTh,
                                                  unsigned short* __restrict__ VTl) {
  __shared__ float wls[96 * 33];
  __shared__ float xs[8 * 33];
  const int tid = threadIdx.x;
  const int r = tid >> 5, j = tid & 31;
  const int row = blockIdx.x * 8 + r;
  for (int i = tid; i < 96 * 32; i += 256) wls[(i >> 5) * 33 + (i & 31)] = wqkv[i];
  xs[(tid >> 5) * 33 + (tid & 31)] = x[(size_t)(blockIdx.x * 8 + (tid >> 5)) * 32 + (tid & 31)];
  __syncthreads();
  float aq = bqkv[j], ak = bqkv[32 + j], av = bqkv[64 + j];
#pragma unroll
  for (int k = 0; k < 32; ++k) {
    const float xv = xs[r * 33 + k];
    aq += xv * wls[j * 33 + k];
    ak += xv * wls[(32 + j) * 33 + k];
    av += xv * wls[(64 + j) * 33 + k];
  }
  const float QSCALE = 1.4426950408889634f * 0.17677669529663687f;  // log2e/sqrt(32)
  aq *= QSCALE;
  unsigned short qh = f2bf(aq);
  unsigned short ql = f2bf(aq - bf2f(qh));
  unsigned short kh = f2bf(ak);
  unsigned short kl = f2bf(ak - bf2f(kh));
  unsigned short vh = f2bf(av);
  unsigned short vl = f2bf(av - bf2f(vh));
  Qh[row * 32 + j] = qh;  Ql[row * 32 + j] = ql;
  Kh[row * 32 + j] = kh;  Kl[row * 32 + j] = kl;
  VTh[j * N_NODES + row] = vh;  VTl[j * N_NODES + row] = vl;
}

// ---------------- MFMA flash attention (bf16x3), swapped-QK^T ----------------
// grid (512 qtiles, 4 ranges) x 4 waves; wave covers 512 keys (16 iters of 32).
// In-block LDS combine of the 4 waves -> one partial (unnorm O + m,l) per (qtile,range).

__global__ void __launch_bounds__(256) attn_mfma_kernel(
    const unsigned short* __restrict__ Qh, const unsigned short* __restrict__ Ql,
    const unsigned short* __restrict__ Kh, const unsigned short* __restrict__ Kl,
    const unsigned short* __restrict__ VTh, const unsigned short* __restrict__ VTl,
    float* __restrict__ part) {
  __shared__ float lds[4][544];
  __shared__ float wexp[4][16];
  __shared__ float Mq[16], Lq[16];
  const int tid = threadIdx.x;
  const int wid = tid >> 6;
  const int lane = tid & 63;
  const int g = lane >> 4;
  const int li = lane & 15;
  const int qtile = blockIdx.x;
  const int q0 = qtile * 16;
  const int kbeg = blockIdx.y * 2048 + wid * 512;

  const short8v qfh = *(const short8v*)&Qh[(q0 + li) * 32 + 8 * g];
  const short8v qfl = *(const short8v*)&Ql[(q0 + li) * 32 + 8 * g];

  const int koff = li * 32 + 8 * g;
  const unsigned short* pVhA = VTh + (size_t)li * N_NODES;
  const unsigned short* pVhB = VTh + (size_t)(16 + li) * N_NODES;
  const unsigned short* pVlA = VTl + (size_t)li * N_NODES;
  const unsigned short* pVlB = VTl + (size_t)(16 + li) * N_NODES;

  f32x4 oA = {0.f, 0.f, 0.f, 0.f};
  f32x4 oB = {0.f, 0.f, 0.f, 0.f};
  float m = -1e30f, l = 0.f;

  for (int t = kbeg; t < kbeg + 512; t += 32) {
    const short8v k0h = *(const short8v*)&Kh[t * 32 + koff];
    const short8v k0l = *(const short8v*)&Kl[t * 32 + koff];
    const short8v k1h = *(const short8v*)&Kh[(t + 16) * 32 + koff];
    const short8v k1l = *(const short8v*)&Kl[(t + 16) * 32 + koff];

    f32x4 s0 = {0.f, 0.f, 0.f, 0.f}, s1 = {0.f, 0.f, 0.f, 0.f};
    s0 = __builtin_amdgcn_mfma_f32_16x16x32_bf16(k0h, qfh, s0, 0, 0, 0);
    s0 = __builtin_amdgcn_mfma_f32_16x16x32_bf16(k0l, qfh, s0, 0, 0, 0);
    s0 = __builtin_amdgcn_mfma_f32_16x16x32_bf16(k0h, qfl, s0, 0, 0, 0);
    s1 = __builtin_amdgcn_mfma_f32_16x16x32_bf16(k1h, qfh, s1, 0, 0, 0);
    s1 = __builtin_amdgcn_mfma_f32_16x16x32_bf16(k1l, qfh, s1, 0, 0, 0);
    s1 = __builtin_amdgcn_mfma_f32_16x16x32_bf16(k1h, qfl, s1, 0, 0, 0);

    float mx = fmaxf(fmaxf(fmaxf(s0[0], s0[1]), fmaxf(s0[2], s0[3])),
                     fmaxf(fmaxf(s1[0], s1[1]), fmaxf(s1[2], s1[3])));
    mx = fmaxf(mx, __shfl_xor(mx, 16, 64));
    mx = fmaxf(mx, __shfl_xor(mx, 32, 64));
    const float mnew = fmaxf(m, mx);
    const float fct = exp2f(m - mnew);
    m = mnew;
    const float p0 = exp2f(s0[0] - mnew), p1 = exp2f(s0[1] - mnew);
    const float p2 = exp2f(s0[2] - mnew), p3 = exp2f(s0[3] - mnew);
    const float p4 = exp2f(s1[0] - mnew), p5 = exp2f(s1[1] - mnew);
    const float p6 = exp2f(s1[2] - mnew), p7 = exp2f(s1[3] - mnew);
    float ls = ((p0 + p1) + (p2 + p3)) + ((p4 + p5) + (p6 + p7));
    ls += __shfl_xor(ls, 16, 64);
    ls += __shfl_xor(ls, 32, 64);
    l = l * fct + ls;
    oA *= fct;
    oB *= fct;

    U8 ph, pl;
    ph.u[0] = cvt_pk_bf16(p0, p1);
    ph.u[1] = cvt_pk_bf16(p2, p3);
    ph.u[2] = cvt_pk_bf16(p4, p5);
    ph.u[3] = cvt_pk_bf16(p6, p7);
    const float h0 = __uint_as_float(ph.u[0] << 16), h1 = __uint_as_float(ph.u[0] & 0xffff0000u);
    const float h2 = __uint_as_float(ph.u[1] << 16), h3 = __uint_as_float(ph.u[1] & 0xffff0000u);
    const float h4 = __uint_as_float(ph.u[2] << 16), h5 = __uint_as_float(ph.u[2] & 0xffff0000u);
    const float h6 = __uint_as_float(ph.u[3] << 16), h7 = __uint_as_float(ph.u[3] & 0xffff0000u);
    pl.u[0] = cvt_pk_bf16(p0 - h0, p1 - h1);
    pl.u[1] = cvt_pk_bf16(p2 - h2, p3 - h3);
    pl.u[2] = cvt_pk_bf16(p4 - h4, p5 - h5);
    pl.u[3] = cvt_pk_bf16(p6 - h6, p7 - h7);

    U8 vhA, vlA, vhB, vlB;
    vhA.h[0] = *(const short4v*)&pVhA[t + 4 * g];
    vhA.h[1] = *(const short4v*)&pVhA[t + 16 + 4 * g];
    vlA.h[0] = *(const short4v*)&pVlA[t + 4 * g];
    vlA.h[1] = *(const short4v*)&pVlA[t + 16 + 4 * g];
    vhB.h[0] = *(const short4v*)&pVhB[t + 4 * g];
    vhB.h[1] = *(const short4v*)&pVhB[t + 16 + 4 * g];
    vlB.h[0] = *(const short4v*)&pVlB[t + 4 * g];
    vlB.h[1] = *(const short4v*)&pVlB[t + 16 + 4 * g];

    oA = __builtin_amdgcn_mfma_f32_16x16x32_bf16(vhA.s8, ph.s8, oA, 0, 0, 0);
    oA = __builtin_amdgcn_mfma_f32_16x16x32_bf16(vlA.s8, ph.s8, oA, 0, 0, 0);
    oA = __builtin_amdgcn_mfma_f32_16x16x32_bf16(vhA.s8, pl.s8, oA, 0, 0, 0);
    oB = __builtin_amdgcn_mfma_f32_16x16x32_bf16(vhB.s8, ph.s8, oB, 0, 0, 0);
    oB = __builtin_amdgcn_mfma_f32_16x16x32_bf16(vlB.s8, ph.s8, oB, 0, 0, 0);
    oB = __builtin_amdgcn_mfma_f32_16x16x32_bf16(vhB.s8, pl.s8, oB, 0, 0, 0);
  }

  // per-wave store into LDS
#pragma unroll
  for (int r = 0; r < 4; ++r) {
    lds[wid][(4 * g + r) * 16 + li] = oA[r];
    lds[wid][(16 + 4 * g + r) * 16 + li] = oB[r];
  }
  if (g == 0) {
    lds[wid][512 + li] = m;
    lds[wid][528 + li] = l;
  }
  __syncthreads();
  if (tid < 16) {
    const int q = tid;
    const float m0 = lds[0][512 + q], m1 = lds[1][512 + q];
    const float m2 = lds[2][512 + q], m3 = lds[3][512 + q];
    const float M = fmaxf(fmaxf(m0, m1), fmaxf(m2, m3));
    const float w0 = exp2f(m0 - M), w1 = exp2f(m1 - M);
    const float w2 = exp2f(m2 - M), w3 = exp2f(m3 - M);
    wexp[0][q] = w0; wexp[1][q] = w1; wexp[2][q] = w2; wexp[3][q] = w3;
    Mq[q] = M;
    Lq[q] = w0 * lds[0][528 + q] + w1 * lds[1][528 + q] +
            w2 * lds[2][528 + q] + w3 * lds[3][528 + q];
  }
  __syncthreads();
  const int base = (qtile * 4 + blockIdx.y) * 544;
#pragma unroll
  for (int e2 = 0; e2 < 2; ++e2) {
    const int e = tid + e2 * 256;
    const int q = e & 15;
    part[base + e] = wexp[0][q] * lds[0][e] + wexp[1][q] * lds[1][e] +
                     wexp[2][q] * lds[2][e] + wexp[3][q] * lds[3][e];
  }
  if (tid < 16) {
    part[base + 512 + tid] = Mq[tid];
    part[base + 528 + tid] = Lq[tid];
  }
}

// ---------------- combine partials over 4 ranges + fused wo projection ----------------
// 128 blocks x 256 threads; wave handles one qtile (16 q rows x 32 dims).

__global__ void __launch_bounds__(256) attn_combine_wo(const float* __restrict__ part,
                                                       const float* __restrict__ wo,
                                                       const float* __restrict__ bo,
                                                       float* __restrict__ out) {
  __shared__ float wols[1024];
  __shared__ float bos[32];
  __shared__ float aos[4][16][33];
  const int tid = threadIdx.x;
  for (int i = tid; i < 1024; i += 256) wols[i] = wo[i];
  if (tid < 32) bos[tid] = bo[tid];
  const int wv = tid >> 6, lane = tid & 63;
  const int qt = blockIdx.x * 4 + wv;
  const int q = lane & 15, g = lane >> 4;
  const int pb = qt * 4 * 544;
  const float m0 = part[pb + 512 + q], m1 = part[pb + 544 + 512 + q];
  const float m2 = part[pb + 1088 + 512 + q], m3 = part[pb + 1632 + 512 + q];
  const float M = fmaxf(fmaxf(m0, m1), fmaxf(m2, m3));
  const float w0 = exp2f(m0 - M), w1 = exp2f(m1 - M);
  const float w2 = exp2f(m2 - M), w3 = exp2f(m3 - M);
  const float L = w0 * part[pb + 528 + q] + w1 * part[pb + 544 + 528 + q] +
                  w2 * part[pb + 1088 + 528 + q] + w3 * part[pb + 1632 + 528 + q];
  const float invL = 1.0f / L;
#pragma unroll
  for (int r = 0; r < 8; ++r) {
    const int d = g + 4 * r;
    const int o = d * 16 + q;
    const float ov = w0 * part[pb + o] + w1 * part[pb + 544 + o] +
                     w2 * part[pb + 1088 + o] + w3 * part[pb + 1632 + o];
    aos[wv][q][d] = ov * invL;
  }
  __syncthreads();
#pragma unroll
  for (int r = 0; r < 8; ++r) {
    const int dout = g + 4 * r;
    float acc = bos[dout];
#pragma unroll
    for (int k = 0; k < 32; ++k) acc += aos[wv][q][k] * wols[dout * 32 + k];
    out[(size_t)(qt * 16 + q) * 32 + dout] = acc;
  }
}

// ---------------- launch ----------------

extern "C" void kernel_launch(void* const* d_in, const int* in_sizes, int n_in,
                              void* d_out, int out_size, void* d_ws, size_t ws_size,
                              hipStream_t stream) {
  (void)in_sizes; (void)n_in; (void)out_size; (void)ws_size;
  const int* adj = (const int*)d_in[0];
  const float* feat = (const float*)d_in[1];
  const float* w1 = (const float*)d_in[2];  const float* b1 = (const float*)d_in[3];
  const float* w2 = (const float*)d_in[4];  const float* b2 = (const float*)d_in[5];
  const float* w3 = (const float*)d_in[6];  const float* b3 = (const float*)d_in[7];
  const float* wqkv = (const float*)d_in[8];const float* bqkv = (const float*)d_in[9];
  const float* wo = (const float*)d_in[10]; const float* bo = (const float*)d_in[11];
  const float* w4 = (const float*)d_in[12]; const float* b4 = (const float*)d_in[13];
  const float* w5a = (const float*)d_in[14];const float* b5a = (const float*)d_in[15];
  const float* w6a = (const float*)d_in[16];const float* b6a = (const float*)d_in[17];
  const float* w7a = (const float*)d_in[18];const float* b7a = (const float*)d_in[19];
  const float* w5f = (const float*)d_in[20];const float* b5f = (const float*)d_in[21];
  const float* w6f = (const float*)d_in[22];const float* b6f = (const float*)d_in[23];
  const float* w7f = (const float*)d_in[24];const float* b7f = (const float*)d_in[25];
  float* outp = (float*)d_out;

  float* wsf = (float*)d_ws;
  int* wsi = (int*)d_ws;
  int* cnt = wsi;                 // 8192
  int* cur = wsi + 8192;          // 8192
  int* rp = wsi + 16384;          // 8193
  float* dinv = wsf + 24832;      // 8192
  float* wgt = wsf + 33024;       // 262144
  int* col = wsi + 295168;        // 262144
  float* T = wsf + 557312;        // 8192*128
  float* B0 = wsf + 1605888;      // 8192*64
  float* B1 = wsf + 2130176;      // 8192*32
  float* B2 = wsf + 2392320;      // 8192*64  (end 2916608)
  unsigned short* Qh = (unsigned short*)(wsf + 2916608);
  unsigned short* Ql = Qh + 131072;
  unsigned short* Kh = Ql + 131072;
  unsigned short* Kl = Kh + 131072;
  unsigned short* VTh = Kl + 131072;
  unsigned short* VTl = VTh + 131072;
  // attention partials: 512 qtiles x 4 ranges x 544 f32 = 1,114,112 f32
  // lives in T (+ head of B0, dead after qkv_kernel)
  float* part = T;

  const int* src = adj;
  const int* dst = adj + N_EDGES;

  hipMemsetAsync(cnt, 0, 2 * N_NODES * sizeof(int), stream);  // cnt + cur
  count_kernel<<<N_EDGES / 256, 256, 0, stream>>>(dst, cnt);
  scan_kernel<<<1, 1024, 0, stream>>>(cnt, rp, dinv);
  fill_kernel<<<N_EDGES / 256, 256, 0, stream>>>(src, dst, rp, dinv, cur, col, wgt);

  // gcn1: 128 -> 64
  mm_kernel<128, 64, false, false><<<N_NODES / 16, 256, 0, stream>>>(feat, w1, nullptr, T);
  aggv_kernel<64><<<N_NODES / 4, 256, 0, stream>>>(T, rp, col, wgt, dinv, b1, B0);
  // gcn2: 64 -> 32
  mm_kernel<64, 32, false, false><<<N_NODES / 32, 256, 0, stream>>>(B0, w2, nullptr, T);
  aggv_kernel<32><<<N_NODES / 4, 256, 0, stream>>>(T, rp, col, wgt, dinv, b2, B1);
  // gcn3: 32 -> 32
  mm_kernel<32, 32, false, false><<<N_NODES / 32, 256, 0, stream>>>(B1, w3, nullptr, T);
  aggv_kernel<32><<<N_NODES / 4, 256, 0, stream>>>(T, rp, col, wgt, dinv, b3, B0);  // h3 in B0

  // attention
  qkv_kernel<<<N_NODES / 8, 256, 0, stream>>>(B0, wqkv, bqkv, Qh, Ql, Kh, Kl, VTh, VTl);
  {
    dim3 grid(512, 4);
    attn_mfma_kernel<<<grid, 256, 0, stream>>>(Qh, Ql, Kh, Kl, VTh, VTl, part);
  }
  attn_combine_wo<<<128, 256, 0, stream>>>(part, wo, bo, B2);  // h_attn in B2

  // gcn4: 32 -> 32
  mm_kernel<32, 32, false, false><<<N_NODES / 32, 256, 0, stream>>>(B2, w4, nullptr, T);
  aggv_kernel<32><<<N_NODES / 4, 256, 0, stream>>>(T, rp, col, wgt, dinv, b4, B0);  // h4 in B0

  // da head: 32->32->64->2
  mm_kernel<32, 32, false, false><<<N_NODES / 32, 256, 0, stream>>>(B0, w5a, nullptr, T);
  aggv_kernel<32><<<N_NODES / 4, 256, 0, stream>>>(T, rp, col, wgt, dinv, b5a, B1);
  mm_kernel<32, 64, false, false><<<N_NODES / 16, 256, 0, stream>>>(B1, w6a, nullptr, T);
  aggv_kernel<64><<<N_NODES / 4, 256, 0, stream>>>(T, rp, col, wgt, dinv, b6a, B2);
  mm_kernel<64, 2, false, false><<<N_NODES / 128, 256, 0, stream>>>(B2, w7a, nullptr, T);
  agg_kernel<2><<<N_NODES / 128, 256, 0, stream>>>(T, rp, col, wgt, dinv, b7a, outp);

  // df head: 32->32->64->128
  mm_kernel<32, 32, false, false><<<N_NODES / 32, 256, 0, stream>>>(B0, w5f, nullptr, T);
  aggv_kernel<32><<<N_NODES / 4, 256, 0, stream>>>(T, rp, col, wgt, dinv, b5f, B1);
  mm_kernel<32, 64, false, false><<<N_NODES / 16, 256, 0, stream>>>(B1, w6f, nullptr, T);
  aggv_kernel<64><<<N_NODES / 4, 256, 0, stream>>>(T, rp, col, wgt, dinv, b6f, B2);
  mm_kernel<64, 128, false, false><<<N_NODES / 8, 256, 0, stream>>>(B2, w7f, nullptr, T);
  aggv_kernel<128><<<N_NODES / 4, 256, 0, stream>>>(T, rp, col, wgt, dinv, b7f, outp + 16384);
}

// Round 4
// 286.367 us; speedup vs baseline: 2.3270x; 1.1909x over previous
//
#include <hip/hip_runtime.h>

#define N_NODES 8192
#define N_EDGES 262144

typedef __attribute__((ext_vector_type(8))) short short8v;
typedef __attribute__((ext_vector_type(4))) short short4v;
typedef __attribute__((ext_vector_type(4))) float f32x4;

union U8 { short8v s8; short4v h[2]; unsigned u[4]; };

__device__ inline unsigned short f2bf(float f) {
  union { float f; unsigned u; } v; v.f = f;
  unsigned r = v.u + 0x7fffu + ((v.u >> 16) & 1u);
  return (unsigned short)(r >> 16);
}
__device__ inline float bf2f(unsigned short b) {
  union { unsigned u; float f; } v; v.u = ((unsigned)b) << 16;
  return v.f;
}
__device__ inline unsigned cvt_pk_bf16(float lo, float hi) {
  unsigned r;
  asm("v_cvt_pk_bf16_f32 %0, %1, %2" : "=v"(r) : "v"(lo), "v"(hi));
  return r;
}

// ---------------- CSR build ----------------

__global__ void __launch_bounds__(256) count_kernel(const int* __restrict__ dst,
                                                    int* __restrict__ cnt) {
  int e = blockIdx.x * 256 + threadIdx.x;
  atomicAdd(&cnt[dst[e]], 1);
}

__global__ void __launch_bounds__(1024) scan_kernel(const int* __restrict__ cnt,
                                                    int* __restrict__ rp,
                                                    float* __restrict__ dinv) {
  __shared__ int sums[1024];
  const int t = threadIdx.x;
  const int base = t * 8;
  int c[8];
  int s = 0;
#pragma unroll
  for (int i = 0; i < 8; ++i) { c[i] = cnt[base + i]; s += c[i]; }
  sums[t] = s;
  __syncthreads();
  for (int off = 1; off < 1024; off <<= 1) {
    int v = (t >= off) ? sums[t - off] : 0;
    __syncthreads();
    sums[t] += v;
    __syncthreads();
  }
  int run = (t == 0) ? 0 : sums[t - 1];
#pragma unroll
  for (int i = 0; i < 8; ++i) {
    rp[base + i] = run;
    run += c[i];
    dinv[base + i] = rsqrtf((float)(c[i] + 1));
  }
  if (t == 1023) rp[N_NODES] = run;
}

__global__ void __launch_bounds__(256) fill_kernel(const int* __restrict__ src,
                                                   const int* __restrict__ dst,
                                                   const int* __restrict__ rp,
                                                   const float* __restrict__ dinv,
                                                   int* __restrict__ cur,
                                                   int* __restrict__ col,
                                                   float* __restrict__ wgt) {
  int e = blockIdx.x * 256 + threadIdx.x;
  int d = dst[e], s = src[e];
  int p = atomicAdd(&cur[d], 1);
  int at = rp[d] + p;
  col[at] = s;
  wgt[at] = dinv[s] * dinv[d];
}

// ---------------- dense matmul ----------------

template <int FIN, int FOUT, bool WT, bool BIAS>
__global__ void __launch_bounds__(256) mm_kernel(const float* __restrict__ x,
                                                 const float* __restrict__ w,
                                                 const float* __restrict__ bias,
                                                 float* __restrict__ out) {
  constexpr int VEC = (FOUT >= 32) ? 4 : 1;
  constexpr int TC = FOUT / VEC;
  constexpr int ROWS = 256 / TC;
  __shared__ float ws[FIN * FOUT];
  __shared__ float xs[ROWS * (FIN + 1)];
  const int tid = threadIdx.x;
  const int r0 = blockIdx.x * ROWS;
  for (int i = tid; i < FIN * FOUT; i += 256) {
    int k = i / FOUT, j = i % FOUT;
    ws[i] = WT ? w[j * FIN + k] : w[i];
  }
  for (int i = tid; i < ROWS * FIN; i += 256) {
    int r = i / FIN, k = i % FIN;
    xs[r * (FIN + 1) + k] = x[(size_t)(r0 + r) * FIN + k];
  }
  __syncthreads();
  const int jc = tid % TC, r = tid / TC;
  float acc[VEC];
#pragma unroll
  for (int v = 0; v < VEC; ++v) acc[v] = 0.0f;
#pragma unroll
  for (int k = 0; k < FIN; ++k) {
    const float xv = xs[r * (FIN + 1) + k];
#pragma unroll
    for (int v = 0; v < VEC; ++v) acc[v] += xv * ws[k * FOUT + jc * VEC + v];
  }
#pragma unroll
  for (int v = 0; v < VEC; ++v) {
    int j = jc * VEC + v;
    out[(size_t)(r0 + r) * FOUT + j] = BIAS ? (acc[v] + bias[j]) : acc[v];
  }
}

// ---------------- GCN aggregation: one wave per node, float4, multi-edge ILP ----------------

template <int F>
__global__ void __launch_bounds__(256) aggv_kernel(const float* __restrict__ t,
                                                   const int* __restrict__ rp,
                                                   const int* __restrict__ col,
                                                   const float* __restrict__ wgt,
                                                   const float* __restrict__ dinv,
                                                   const float* __restrict__ bias,
                                                   float* __restrict__ out) {
  constexpr int TPN = F / 4;
  constexpr int EPI = 64 / TPN;
  const int tid = threadIdx.x;
  const int wv = tid >> 6;
  const int lane = tid & 63;
  const int n = blockIdx.x * 4 + wv;
  const int eo = lane / TPN;
  const int fq = lane % TPN;
  const float di = dinv[n];
  const int rs = rp[n], re = rp[n + 1];
  f32x4 acc = {0.f, 0.f, 0.f, 0.f};
  if (eo == 0) {
    const f32x4 tv = *(const f32x4*)&t[(size_t)n * F + fq * 4];
    acc = di * di * tv;
  }
  for (int e = rs + eo; e < re; e += EPI) {
    const int c = col[e];
    const float w = wgt[e];
    const f32x4 tv = *(const f32x4*)&t[(size_t)c * F + fq * 4];
    acc += w * tv;
  }
#pragma unroll
  for (int off = TPN; off < 64; off <<= 1) {
    acc[0] += __shfl_xor(acc[0], off, 64);
    acc[1] += __shfl_xor(acc[1], off, 64);
    acc[2] += __shfl_xor(acc[2], off, 64);
    acc[3] += __shfl_xor(acc[3], off, 64);
  }
  if (eo == 0) {
    const f32x4 bv = *(const f32x4*)&bias[fq * 4];
    f32x4 r = acc + bv;
    r[0] = fmaxf(r[0], 0.f); r[1] = fmaxf(r[1], 0.f);
    r[2] = fmaxf(r[2], 0.f); r[3] = fmaxf(r[3], 0.f);
    *(f32x4*)&out[(size_t)n * F + fq * 4] = r;
  }
}

// F=2 tail layer (da head output)
template <int F>
__global__ void __launch_bounds__(256) agg_kernel(const float* __restrict__ t,
                                                  const int* __restrict__ rp,
                                                  const int* __restrict__ col,
                                                  const float* __restrict__ wgt,
                                                  const float* __restrict__ dinv,
                                                  const float* __restrict__ bias,
                                                  float* __restrict__ out) {
  constexpr int NPB = 256 / F;
  const int tid = threadIdx.x;
  const int n = blockIdx.x * NPB + tid / F;
  const int f = tid % F;
  const float di = dinv[n];
  float acc = di * di * t[(size_t)n * F + f];
  const int rs = rp[n], re = rp[n + 1];
  for (int e = rs; e < re; ++e) {
    acc += wgt[e] * t[(size_t)col[e] * F + f];
  }
  acc += bias[f];
  out[(size_t)n * F + f] = fmaxf(acc, 0.0f);
}

// ---------------- fused QKV projection -> bf16 hi/lo buffers ----------------
// V^T stored kappa-swizzled: within each 32-key block, key ko -> slot
// 8*((ko&15)>>2) + 4*(ko>>4) + (ko&3), so a PV A-fragment is one contiguous short8v.

__global__ void __launch_bounds__(256) qkv_kernel(const float* __restrict__ x,
                                                  const float* __restrict__ wqkv,
                                                  const float* __restrict__ bqkv,
                                                  unsigned short* __restrict__ Qh,
                                                  unsigned short* __restrict__ Ql,
                                                  unsigned short* __restrict__ Kh,
                                                  unsigned short* __restrict__ Kl,
                                                  unsigned short* __restrict__ VSh,
                                                  unsigned short* __restrict__ VSl) {
  __shared__ float wls[96 * 33];
  __shared__ float xs[8 * 33];
  const int tid = threadIdx.x;
  const int r = tid >> 5, j = tid & 31;
  const int row = blockIdx.x * 8 + r;
  for (int i = tid; i < 96 * 32; i += 256) wls[(i >> 5) * 33 + (i & 31)] = wqkv[i];
  xs[(tid >> 5) * 33 + (tid & 31)] = x[(size_t)(blockIdx.x * 8 + (tid >> 5)) * 32 + (tid & 31)];
  __syncthreads();
  float aq = bqkv[j], ak = bqkv[32 + j], av = bqkv[64 + j];
#pragma unroll
  for (int k = 0; k < 32; ++k) {
    const float xv = xs[r * 33 + k];
    aq += xv * wls[j * 33 + k];
    ak += xv * wls[(32 + j) * 33 + k];
    av += xv * wls[(64 + j) * 33 + k];
  }
  const float QSCALE = 1.4426950408889634f * 0.17677669529663687f;  // log2e/sqrt(32)
  aq *= QSCALE;
  unsigned short qh = f2bf(aq);
  unsigned short ql = f2bf(aq - bf2f(qh));
  unsigned short kh = f2bf(ak);
  unsigned short kl = f2bf(ak - bf2f(kh));
  unsigned short vh = f2bf(av);
  unsigned short vl = f2bf(av - bf2f(vh));
  Qh[row * 32 + j] = qh;  Ql[row * 32 + j] = ql;
  Kh[row * 32 + j] = kh;  Kl[row * 32 + j] = kl;
  const int ko = row & 31;
  const int slot = 8 * ((ko & 15) >> 2) + ((ko >> 4) << 2) + (ko & 3);
  const int vidx = j * N_NODES + (row & ~31) + slot;
  VSh[vidx] = vh;  VSl[vidx] = vl;
}

// ---------------- MFMA flash attention (bf16x3), swapped-QK^T ----------------
// grid (512 qtiles, 4 ranges) x 4 waves; wave covers 512 keys (16 iters of 32).
// __launch_bounds__(256,4): cap 128 VGPR (4 waves/EU) -> no scratch spill.

__global__ void __launch_bounds__(256, 4) attn_mfma_kernel(
    const unsigned short* __restrict__ Qh, const unsigned short* __restrict__ Ql,
    const unsigned short* __restrict__ Kh, const unsigned short* __restrict__ Kl,
    const unsigned short* __restrict__ VSh, const unsigned short* __restrict__ VSl,
    float* __restrict__ part) {
  __shared__ float lds[4][544];
  __shared__ float wexp[4][16];
  __shared__ float Mq[16], Lq[16];
  const int tid = threadIdx.x;
  const int wid = tid >> 6;
  const int lane = tid & 63;
  const int g = lane >> 4;
  const int li = lane & 15;
  const int qtile = blockIdx.x;
  const int q0 = qtile * 16;
  const int kbeg = blockIdx.y * 2048 + wid * 512;

  const short8v qfh = *(const short8v*)&Qh[(q0 + li) * 32 + 8 * g];
  const short8v qfl = *(const short8v*)&Ql[(q0 + li) * 32 + 8 * g];

  const int koff = li * 32 + 8 * g;
  const int vA = li * N_NODES + 8 * g;         // row li, slot 8g
  const int vB = (16 + li) * N_NODES + 8 * g;  // row 16+li

  f32x4 oA = {0.f, 0.f, 0.f, 0.f};
  f32x4 oB = {0.f, 0.f, 0.f, 0.f};
  float m = -1e30f, l = 0.f;

  for (int t = kbeg; t < kbeg + 512; t += 32) {
    const short8v k0h = *(const short8v*)&Kh[t * 32 + koff];
    const short8v k0l = *(const short8v*)&Kl[t * 32 + koff];
    const short8v k1h = *(const short8v*)&Kh[(t + 16) * 32 + koff];
    const short8v k1l = *(const short8v*)&Kl[(t + 16) * 32 + koff];

    f32x4 s0 = {0.f, 0.f, 0.f, 0.f}, s1 = {0.f, 0.f, 0.f, 0.f};
    s0 = __builtin_amdgcn_mfma_f32_16x16x32_bf16(k0h, qfh, s0, 0, 0, 0);
    s0 = __builtin_amdgcn_mfma_f32_16x16x32_bf16(k0l, qfh, s0, 0, 0, 0);
    s0 = __builtin_amdgcn_mfma_f32_16x16x32_bf16(k0h, qfl, s0, 0, 0, 0);
    s1 = __builtin_amdgcn_mfma_f32_16x16x32_bf16(k1h, qfh, s1, 0, 0, 0);
    s1 = __builtin_amdgcn_mfma_f32_16x16x32_bf16(k1l, qfh, s1, 0, 0, 0);
    s1 = __builtin_amdgcn_mfma_f32_16x16x32_bf16(k1h, qfl, s1, 0, 0, 0);

    float mx = fmaxf(fmaxf(fmaxf(s0[0], s0[1]), fmaxf(s0[2], s0[3])),
                     fmaxf(fmaxf(s1[0], s1[1]), fmaxf(s1[2], s1[3])));
    mx = fmaxf(mx, __shfl_xor(mx, 16, 64));
    mx = fmaxf(mx, __shfl_xor(mx, 32, 64));
    const float mnew = fmaxf(m, mx);
    const float fct = exp2f(m - mnew);
    m = mnew;
    const float p0 = exp2f(s0[0] - mnew), p1 = exp2f(s0[1] - mnew);
    const float p2 = exp2f(s0[2] - mnew), p3 = exp2f(s0[3] - mnew);
    const float p4 = exp2f(s1[0] - mnew), p5 = exp2f(s1[1] - mnew);
    const float p6 = exp2f(s1[2] - mnew), p7 = exp2f(s1[3] - mnew);
    float ls = ((p0 + p1) + (p2 + p3)) + ((p4 + p5) + (p6 + p7));
    ls += __shfl_xor(ls, 16, 64);
    ls += __shfl_xor(ls, 32, 64);
    l = l * fct + ls;
    oA *= fct;
    oB *= fct;

    U8 ph, pl;
    ph.u[0] = cvt_pk_bf16(p0, p1);
    ph.u[1] = cvt_pk_bf16(p2, p3);
    ph.u[2] = cvt_pk_bf16(p4, p5);
    ph.u[3] = cvt_pk_bf16(p6, p7);
    const float h0 = __uint_as_float(ph.u[0] << 16), h1 = __uint_as_float(ph.u[0] & 0xffff0000u);
    const float h2 = __uint_as_float(ph.u[1] << 16), h3 = __uint_as_float(ph.u[1] & 0xffff0000u);
    const float h4 = __uint_as_float(ph.u[2] << 16), h5 = __uint_as_float(ph.u[2] & 0xffff0000u);
    const float h6 = __uint_as_float(ph.u[3] << 16), h7 = __uint_as_float(ph.u[3] & 0xffff0000u);
    pl.u[0] = cvt_pk_bf16(p0 - h0, p1 - h1);
    pl.u[1] = cvt_pk_bf16(p2 - h2, p3 - h3);
    pl.u[2] = cvt_pk_bf16(p4 - h4, p5 - h5);
    pl.u[3] = cvt_pk_bf16(p6 - h6, p7 - h7);

    const short8v vhA = *(const short8v*)&VSh[vA + t];
    const short8v vlA = *(const short8v*)&VSl[vA + t];
    const short8v vhB = *(const short8v*)&VSh[vB + t];
    const short8v vlB = *(const short8v*)&VSl[vB + t];

    oA = __builtin_amdgcn_mfma_f32_16x16x32_bf16(vhA, ph.s8, oA, 0, 0, 0);
    oA = __builtin_amdgcn_mfma_f32_16x16x32_bf16(vlA, ph.s8, oA, 0, 0, 0);
    oA = __builtin_amdgcn_mfma_f32_16x16x32_bf16(vhA, pl.s8, oA, 0, 0, 0);
    oB = __builtin_amdgcn_mfma_f32_16x16x32_bf16(vhB, ph.s8, oB, 0, 0, 0);
    oB = __builtin_amdgcn_mfma_f32_16x16x32_bf16(vlB, ph.s8, oB, 0, 0, 0);
    oB = __builtin_amdgcn_mfma_f32_16x16x32_bf16(vhB, pl.s8, oB, 0, 0, 0);
  }

  // per-wave store into LDS
#pragma unroll
  for (int r = 0; r < 4; ++r) {
    lds[wid][(4 * g + r) * 16 + li] = oA[r];
    lds[wid][(16 + 4 * g + r) * 16 + li] = oB[r];
  }
  if (g == 0) {
    lds[wid][512 + li] = m;
    lds[wid][528 + li] = l;
  }
  __syncthreads();
  if (tid < 16) {
    const int q = tid;
    const float m0 = lds[0][512 + q], m1 = lds[1][512 + q];
    const float m2 = lds[2][512 + q], m3 = lds[3][512 + q];
    const float M = fmaxf(fmaxf(m0, m1), fmaxf(m2, m3));
    const float w0 = exp2f(m0 - M), w1 = exp2f(m1 - M);
    const float w2 = exp2f(m2 - M), w3 = exp2f(m3 - M);
    wexp[0][q] = w0; wexp[1][q] = w1; wexp[2][q] = w2; wexp[3][q] = w3;
    Mq[q] = M;
    Lq[q] = w0 * lds[0][528 + q] + w1 * lds[1][528 + q] +
            w2 * lds[2][528 + q] + w3 * lds[3][528 + q];
  }
  __syncthreads();
  const int base = (qtile * 4 + blockIdx.y) * 544;
#pragma unroll
  for (int e2 = 0; e2 < 2; ++e2) {
    const int e = tid + e2 * 256;
    const int q = e & 15;
    part[base + e] = wexp[0][q] * lds[0][e] + wexp[1][q] * lds[1][e] +
                     wexp[2][q] * lds[2][e] + wexp[3][q] * lds[3][e];
  }
  if (tid < 16) {
    part[base + 512 + tid] = Mq[tid];
    part[base + 528 + tid] = Lq[tid];
  }
}

// ---------------- combine partials over 4 ranges + fused wo projection ----------------

__global__ void __launch_bounds__(256) attn_combine_wo(const float* __restrict__ part,
                                                       const float* __restrict__ wo,
                                                       const float* __restrict__ bo,
                                                       float* __restrict__ out) {
  __shared__ float wols[1024];
  __shared__ float bos[32];
  __shared__ float aos[4][16][33];
  const int tid = threadIdx.x;
  for (int i = tid; i < 1024; i += 256) wols[i] = wo[i];
  if (tid < 32) bos[tid] = bo[tid];
  const int wv = tid >> 6, lane = tid & 63;
  const int qt = blockIdx.x * 4 + wv;
  const int q = lane & 15, g = lane >> 4;
  const int pb = qt * 4 * 544;
  const float m0 = part[pb + 512 + q], m1 = part[pb + 544 + 512 + q];
  const float m2 = part[pb + 1088 + 512 + q], m3 = part[pb + 1632 + 512 + q];
  const float M = fmaxf(fmaxf(m0, m1), fmaxf(m2, m3));
  const float w0 = exp2f(m0 - M), w1 = exp2f(m1 - M);
  const float w2 = exp2f(m2 - M), w3 = exp2f(m3 - M);
  const float L = w0 * part[pb + 528 + q] + w1 * part[pb + 544 + 528 + q] +
                  w2 * part[pb + 1088 + 528 + q] + w3 * part[pb + 1632 + 528 + q];
  const float invL = 1.0f / L;
#pragma unroll
  for (int r = 0; r < 8; ++r) {
    const int d = g + 4 * r;
    const int o = d * 16 + q;
    const float ov = w0 * part[pb + o] + w1 * part[pb + 544 + o] +
                     w2 * part[pb + 1088 + o] + w3 * part[pb + 1632 + o];
    aos[wv][q][d] = ov * invL;
  }
  __syncthreads();
#pragma unroll
  for (int r = 0; r < 8; ++r) {
    const int dout = g + 4 * r;
    float acc = bos[dout];
#pragma unroll
    for (int k = 0; k < 32; ++k) acc += aos[wv][q][k] * wols[dout * 32 + k];
    out[(size_t)(qt * 16 + q) * 32 + dout] = acc;
  }
}

// ---------------- launch ----------------

extern "C" void kernel_launch(void* const* d_in, const int* in_sizes, int n_in,
                              void* d_out, int out_size, void* d_ws, size_t ws_size,
                              hipStream_t stream) {
  (void)in_sizes; (void)n_in; (void)out_size; (void)ws_size;
  const int* adj = (const int*)d_in[0];
  const float* feat = (const float*)d_in[1];
  const float* w1 = (const float*)d_in[2];  const float* b1 = (const float*)d_in[3];
  const float* w2 = (const float*)d_in[4];  const float* b2 = (const float*)d_in[5];
  const float* w3 = (const float*)d_in[6];  const float* b3 = (const float*)d_in[7];
  const float* wqkv = (const float*)d_in[8];const float* bqkv = (const float*)d_in[9];
  const float* wo = (const float*)d_in[10]; const float* bo = (const float*)d_in[11];
  const float* w4 = (const float*)d_in[12]; const float* b4 = (const float*)d_in[13];
  const float* w5a = (const float*)d_in[14];const float* b5a = (const float*)d_in[15];
  const float* w6a = (const float*)d_in[16];const float* b6a = (const float*)d_in[17];
  const float* w7a = (const float*)d_in[18];const float* b7a = (const float*)d_in[19];
  const float* w5f = (const float*)d_in[20];const float* b5f = (const float*)d_in[21];
  const float* w6f = (const float*)d_in[22];const float* b6f = (const float*)d_in[23];
  const float* w7f = (const float*)d_in[24];const float* b7f = (const float*)d_in[25];
  float* outp = (float*)d_out;

  float* wsf = (float*)d_ws;
  int* wsi = (int*)d_ws;
  int* cnt = wsi;                 // 8192
  int* cur = wsi + 8192;          // 8192
  int* rp = wsi + 16384;          // 8193
  float* dinv = wsf + 24832;      // 8192
  float* wgt = wsf + 33024;       // 262144
  int* col = wsi + 295168;        // 262144
  float* T = wsf + 557312;        // 8192*128
  float* B0 = wsf + 1605888;      // 8192*64
  float* B1 = wsf + 2130176;      // 8192*32
  float* B2 = wsf + 2392320;      // 8192*64  (end 2916608)
  unsigned short* Qh = (unsigned short*)(wsf + 2916608);
  unsigned short* Ql = Qh + 131072;
  unsigned short* Kh = Ql + 131072;
  unsigned short* Kl = Kh + 131072;
  unsigned short* VSh = Kl + 131072;
  unsigned short* VSl = VSh + 131072;
  float* part = T;  // 512 qtiles x 4 ranges x 544 f32

  const int* src = adj;
  const int* dst = adj + N_EDGES;

  hipMemsetAsync(cnt, 0, 2 * N_NODES * sizeof(int), stream);  // cnt + cur
  count_kernel<<<N_EDGES / 256, 256, 0, stream>>>(dst, cnt);
  scan_kernel<<<1, 1024, 0, stream>>>(cnt, rp, dinv);
  fill_kernel<<<N_EDGES / 256, 256, 0, stream>>>(src, dst, rp, dinv, cur, col, wgt);

  // gcn1: 128 -> 64
  mm_kernel<128, 64, false, false><<<N_NODES / 16, 256, 0, stream>>>(feat, w1, nullptr, T);
  aggv_kernel<64><<<N_NODES / 4, 256, 0, stream>>>(T, rp, col, wgt, dinv, b1, B0);
  // gcn2: 64 -> 32
  mm_kernel<64, 32, false, false><<<N_NODES / 32, 256, 0, stream>>>(B0, w2, nullptr, T);
  aggv_kernel<32><<<N_NODES / 4, 256, 0, stream>>>(T, rp, col, wgt, dinv, b2, B1);
  // gcn3: 32 -> 32
  mm_kernel<32, 32, false, false><<<N_NODES / 32, 256, 0, stream>>>(B1, w3, nullptr, T);
  aggv_kernel<32><<<N_NODES / 4, 256, 0, stream>>>(T, rp, col, wgt, dinv, b3, B0);  // h3 in B0

  // attention
  qkv_kernel<<<N_NODES / 8, 256, 0, stream>>>(B0, wqkv, bqkv, Qh, Ql, Kh, Kl, VSh, VSl);
  {
    dim3 grid(512, 4);
    attn_mfma_kernel<<<grid, 256, 0, stream>>>(Qh, Ql, Kh, Kl, VSh, VSl, part);
  }
  attn_combine_wo<<<128, 256, 0, stream>>>(part, wo, bo, B2);  // h_attn in B2

  // gcn4: 32 -> 32
  mm_kernel<32, 32, false, false><<<N_NODES / 32, 256, 0, stream>>>(B2, w4, nullptr, T);
  aggv_kernel<32><<<N_NODES / 4, 256, 0, stream>>>(T, rp, col, wgt, dinv, b4, B0);  // h4 in B0

  // da head: 32->32->64->2
  mm_kernel<32, 32, false, false><<<N_NODES / 32, 256, 0, stream>>>(B0, w5a, nullptr, T);
  aggv_kernel<32><<<N_NODES / 4, 256, 0, stream>>>(T, rp, col, wgt, dinv, b5a, B1);
  mm_kernel<32, 64, false, false><<<N_NODES / 16, 256, 0, stream>>>(B1, w6a, nullptr, T);
  aggv_kernel<64><<<N_NODES / 4, 256, 0, stream>>>(T, rp, col, wgt, dinv, b6a, B2);
  mm_kernel<64, 2, false, false><<<N_NODES / 128, 256, 0, stream>>>(B2, w7a, nullptr, T);
  agg_kernel<2><<<N_NODES / 128, 256, 0, stream>>>(T, rp, col, wgt, dinv, b7a, outp);

  // df head: 32->32->64->128
  mm_kernel<32, 32, false, false><<<N_NODES / 32, 256, 0, stream>>>(B0, w5f, nullptr, T);
  aggv_kernel<32><<<N_NODES / 4, 256, 0, stream>>>(T, rp, col, wgt, dinv, b5f, B1);
  mm_kernel<32, 64, false, false><<<N_NODES / 16, 256, 0, stream>>>(B1, w6f, nullptr, T);
  aggv_kernel<64><<<N_NODES / 4, 256, 0, stream>>>(T, rp, col, wgt, dinv, b6f, B2);
  mm_kernel<64, 128, false, false><<<N_NODES / 8, 256, 0, stream>>>(B2, w7f, nullptr, T);
  aggv_kernel<128><<<N_NODES / 4, 256, 0, stream>>>(T, rp, col, wgt, dinv, b7f, outp + 16384);
}

// Round 6
// 233.866 us; speedup vs baseline: 2.8494x; 1.2245x over previous
//
#include <hip/hip_runtime.h>

#define N_NODES 8192
#define N_EDGES 262144

typedef __attribute__((ext_vector_type(4))) float f32x4;
typedef _Float16 half8 __attribute__((ext_vector_type(8)));
typedef __fp16 fp16x2 __attribute__((ext_vector_type(2)));
union UH { half8 h8; fp16x2 h2[4]; };
union HC { _Float16 h; unsigned short u; };

// ---------------- CSR build ----------------

__global__ void __launch_bounds__(256) count_kernel(const int* __restrict__ dst,
                                                    int* __restrict__ cnt) {
  int e = blockIdx.x * 256 + threadIdx.x;
  atomicAdd(&cnt[dst[e]], 1);
}

__global__ void __launch_bounds__(1024) scan_kernel(const int* __restrict__ cnt,
                                                    int* __restrict__ rp,
                                                    float* __restrict__ dinv) {
  __shared__ int sums[1024];
  const int t = threadIdx.x;
  const int base = t * 8;
  int c[8];
  int s = 0;
#pragma unroll
  for (int i = 0; i < 8; ++i) { c[i] = cnt[base + i]; s += c[i]; }
  sums[t] = s;
  __syncthreads();
  for (int off = 1; off < 1024; off <<= 1) {
    int v = (t >= off) ? sums[t - off] : 0;
    __syncthreads();
    sums[t] += v;
    __syncthreads();
  }
  int run = (t == 0) ? 0 : sums[t - 1];
#pragma unroll
  for (int i = 0; i < 8; ++i) {
    rp[base + i] = run;
    run += c[i];
    dinv[base + i] = rsqrtf((float)(c[i] + 1));
  }
  if (t == 1023) rp[N_NODES] = run;
}

__global__ void __launch_bounds__(256) fill_kernel(const int* __restrict__ src,
                                                   const int* __restrict__ dst,
                                                   const int* __restrict__ rp,
                                                   const float* __restrict__ dinv,
                                                   int* __restrict__ cur,
                                                   int* __restrict__ col,
                                                   float* __restrict__ wgt) {
  int e = blockIdx.x * 256 + threadIdx.x;
  int d = dst[e], s = src[e];
  int p = atomicAdd(&cur[d], 1);
  int at = rp[d] + p;
  col[at] = s;
  wgt[at] = dinv[s] * dinv[d];
}

// ---------------- dense matmul ----------------

template <int FIN, int FOUT, bool WT, bool BIAS, bool RELU = false>
__global__ void __launch_bounds__(256) mm_kernel(const float* __restrict__ x,
                                                 const float* __restrict__ w,
                                                 const float* __restrict__ bias,
                                                 float* __restrict__ out) {
  constexpr int VEC = (FOUT >= 32) ? 4 : 1;
  constexpr int TC = FOUT / VEC;
  constexpr int ROWS = 256 / TC;
  __shared__ float ws[FIN * FOUT];
  __shared__ float xs[ROWS * (FIN + 1)];
  const int tid = threadIdx.x;
  const int r0 = blockIdx.x * ROWS;
  for (int i = tid; i < FIN * FOUT; i += 256) {
    int k = i / FOUT, j = i % FOUT;
    ws[i] = WT ? w[j * FIN + k] : w[i];
  }
  for (int i = tid; i < ROWS * FIN; i += 256) {
    int r = i / FIN, k = i % FIN;
    xs[r * (FIN + 1) + k] = x[(size_t)(r0 + r) * FIN + k];
  }
  __syncthreads();
  const int jc = tid % TC, r = tid / TC;
  float acc[VEC];
#pragma unroll
  for (int v = 0; v < VEC; ++v) acc[v] = 0.0f;
#pragma unroll
  for (int k = 0; k < FIN; ++k) {
    const float xv = xs[r * (FIN + 1) + k];
#pragma unroll
    for (int v = 0; v < VEC; ++v) acc[v] += xv * ws[k * FOUT + jc * VEC + v];
  }
#pragma unroll
  for (int v = 0; v < VEC; ++v) {
    int j = jc * VEC + v;
    float o = BIAS ? (acc[v] + bias[j]) : acc[v];
    if (RELU) o = fmaxf(o, 0.0f);
    out[(size_t)(r0 + r) * FOUT + j] = o;
  }
}

// ---------------- GCN aggregation: one wave per node, float4, multi-edge ILP ----------------
// BR=true: + bias, relu. BR=false: raw normalized aggregation (for gather-before-project).

template <int F, bool BR = true>
__global__ void __launch_bounds__(256) aggv_kernel(const float* __restrict__ t,
                                                   const int* __restrict__ rp,
                                                   const int* __restrict__ col,
                                                   const float* __restrict__ wgt,
                                                   const float* __restrict__ dinv,
                                                   const float* __restrict__ bias,
                                                   float* __restrict__ out) {
  constexpr int TPN = F / 4;
  constexpr int EPI = 64 / TPN;
  const int tid = threadIdx.x;
  const int wv = tid >> 6;
  const int lane = tid & 63;
  const int n = blockIdx.x * 4 + wv;
  const int eo = lane / TPN;
  const int fq = lane % TPN;
  const float di = dinv[n];
  const int rs = rp[n], re = rp[n + 1];
  f32x4 acc = {0.f, 0.f, 0.f, 0.f};
  if (eo == 0) {
    const f32x4 tv = *(const f32x4*)&t[(size_t)n * F + fq * 4];
    acc = di * di * tv;
  }
  for (int e = rs + eo; e < re; e += EPI) {
    const int c = col[e];
    const float w = wgt[e];
    const f32x4 tv = *(const f32x4*)&t[(size_t)c * F + fq * 4];
    acc += w * tv;
  }
#pragma unroll
  for (int off = TPN; off < 64; off <<= 1) {
    acc[0] += __shfl_xor(acc[0], off, 64);
    acc[1] += __shfl_xor(acc[1], off, 64);
    acc[2] += __shfl_xor(acc[2], off, 64);
    acc[3] += __shfl_xor(acc[3], off, 64);
  }
  if (eo == 0) {
    f32x4 r = acc;
    if (BR) {
      const f32x4 bv = *(const f32x4*)&bias[fq * 4];
      r = acc + bv;
      r[0] = fmaxf(r[0], 0.f); r[1] = fmaxf(r[1], 0.f);
      r[2] = fmaxf(r[2], 0.f); r[3] = fmaxf(r[3], 0.f);
    }
    *(f32x4*)&out[(size_t)n * F + fq * 4] = r;
  }
}

// F=2 tail layer (da head output)
template <int F>
__global__ void __launch_bounds__(256) agg_kernel(const float* __restrict__ t,
                                                  const int* __restrict__ rp,
                                                  const int* __restrict__ col,
                                                  const float* __restrict__ wgt,
                                                  const float* __restrict__ dinv,
                                                  const float* __restrict__ bias,
                                                  float* __restrict__ out) {
  constexpr int NPB = 256 / F;
  const int tid = threadIdx.x;
  const int n = blockIdx.x * NPB + tid / F;
  const int f = tid % F;
  const float di = dinv[n];
  float acc = di * di * t[(size_t)n * F + f];
  const int rs = rp[n], re = rp[n + 1];
  for (int e = rs; e < re; ++e) {
    acc += wgt[e] * t[(size_t)col[e] * F + f];
  }
  acc += bias[f];
  out[(size_t)n * F + f] = fmaxf(acc, 0.0f);
}

// ---------------- fused QKV projection -> fp16 buffers ----------------
// Q scaled by log2(e)/sqrt(32). V stored transposed+kappa-swizzled: within each
// 32-key block, key ko -> slot 8*((ko&15)>>2) + 4*(ko>>4) + (ko&3).

__global__ void __launch_bounds__(256) qkv_kernel(const float* __restrict__ x,
                                                  const float* __restrict__ wqkv,
                                                  const float* __restrict__ bqkv,
                                                  unsigned short* __restrict__ Q16,
                                                  unsigned short* __restrict__ K16,
                                                  unsigned short* __restrict__ V16) {
  __shared__ float wls[96 * 33];
  __shared__ float xs[8 * 33];
  const int tid = threadIdx.x;
  const int r = tid >> 5, j = tid & 31;
  const int row = blockIdx.x * 8 + r;
  for (int i = tid; i < 96 * 32; i += 256) wls[(i >> 5) * 33 + (i & 31)] = wqkv[i];
  xs[(tid >> 5) * 33 + (tid & 31)] = x[(size_t)(blockIdx.x * 8 + (tid >> 5)) * 32 + (tid & 31)];
  __syncthreads();
  float aq = bqkv[j], ak = bqkv[32 + j], av = bqkv[64 + j];
#pragma unroll
  for (int k = 0; k < 32; ++k) {
    const float xv = xs[r * 33 + k];
    aq += xv * wls[j * 33 + k];
    ak += xv * wls[(32 + j) * 33 + k];
    av += xv * wls[(64 + j) * 33 + k];
  }
  const float QSCALE = 1.4426950408889634f * 0.17677669529663687f;  // log2e/sqrt(32)
  aq *= QSCALE;
  HC cq, ck, cv;
  cq.h = (_Float16)aq;
  ck.h = (_Float16)ak;
  cv.h = (_Float16)av;
  Q16[row * 32 + j] = cq.u;
  K16[row * 32 + j] = ck.u;
  const int ko = row & 31;
  const int slot = 8 * ((ko & 15) >> 2) + ((ko >> 4) << 2) + (ko & 3);
  V16[j * N_NODES + (row & ~31) + slot] = cv.u;
}

// ---------------- MFMA flash attention (fp16), swapped-QK^T, 64 keys/iter ----------------
// grid (512 qtiles, 4 ranges) x 4 waves; wave covers 512 keys in 8 iterations.
// Exact defer-max: skip rescale when no lane's tile-max exceeds running max (fct==1).

__global__ void __launch_bounds__(256, 4) attn_mfma_kernel(
    const unsigned short* __restrict__ Q16, const unsigned short* __restrict__ K16,
    const unsigned short* __restrict__ V16, float* __restrict__ part) {
  __shared__ float lds[4][544];
  __shared__ float wexp[4][16];
  __shared__ float Mq[16], Lq[16];
  const int tid = threadIdx.x;
  const int wid = tid >> 6;
  const int lane = tid & 63;
  const int g = lane >> 4;
  const int li = lane & 15;
  const int qtile = blockIdx.x;
  const int q0 = qtile * 16;
  const int kbeg = blockIdx.y * 2048 + wid * 512;

  const half8 qf = *(const half8*)&Q16[(q0 + li) * 32 + 8 * g];
  const int koff = li * 32 + 8 * g;
  const int vA = li * N_NODES + 8 * g;
  const int vB = (16 + li) * N_NODES + 8 * g;

  f32x4 oA = {0.f, 0.f, 0.f, 0.f};
  f32x4 oB = {0.f, 0.f, 0.f, 0.f};
  float m = -1e30f, l = 0.f;

  for (int t = kbeg; t < kbeg + 512; t += 64) {
    const half8 k0 = *(const half8*)&K16[(t)*32 + koff];
    const half8 k1 = *(const half8*)&K16[(t + 16) * 32 + koff];
    const half8 k2 = *(const half8*)&K16[(t + 32) * 32 + koff];
    const half8 k3 = *(const half8*)&K16[(t + 48) * 32 + koff];
    const half8 va0 = *(const half8*)&V16[vA + t];
    const half8 vb0 = *(const half8*)&V16[vB + t];
    const half8 va1 = *(const half8*)&V16[vA + t + 32];
    const half8 vb1 = *(const half8*)&V16[vB + t + 32];

    f32x4 s0 = {0.f, 0.f, 0.f, 0.f}, s1 = {0.f, 0.f, 0.f, 0.f};
    f32x4 s2 = {0.f, 0.f, 0.f, 0.f}, s3 = {0.f, 0.f, 0.f, 0.f};
    s0 = __builtin_amdgcn_mfma_f32_16x16x32_f16(k0, qf, s0, 0, 0, 0);
    s1 = __builtin_amdgcn_mfma_f32_16x16x32_f16(k1, qf, s1, 0, 0, 0);
    s2 = __builtin_amdgcn_mfma_f32_16x16x32_f16(k2, qf, s2, 0, 0, 0);
    s3 = __builtin_amdgcn_mfma_f32_16x16x32_f16(k3, qf, s3, 0, 0, 0);

    float mx = fmaxf(fmaxf(fmaxf(s0[0], s0[1]), fmaxf(s0[2], s0[3])),
                     fmaxf(fmaxf(s1[0], s1[1]), fmaxf(s1[2], s1[3])));
    mx = fmaxf(mx, fmaxf(fmaxf(fmaxf(s2[0], s2[1]), fmaxf(s2[2], s2[3])),
                         fmaxf(fmaxf(s3[0], s3[1]), fmaxf(s3[2], s3[3]))));
    mx = fmaxf(mx, __shfl_xor(mx, 16, 64));
    mx = fmaxf(mx, __shfl_xor(mx, 32, 64));
    if (!__all(mx <= m)) {
      const float mn = fmaxf(m, mx);
      const float fct = exp2f(m - mn);
      oA *= fct;
      oB *= fct;
      l *= fct;
      m = mn;
    }
    const float p0 = exp2f(s0[0] - m), p1 = exp2f(s0[1] - m);
    const float p2 = exp2f(s0[2] - m), p3 = exp2f(s0[3] - m);
    const float p4 = exp2f(s1[0] - m), p5 = exp2f(s1[1] - m);
    const float p6 = exp2f(s1[2] - m), p7 = exp2f(s1[3] - m);
    const float p8 = exp2f(s2[0] - m), p9 = exp2f(s2[1] - m);
    const float pa = exp2f(s2[2] - m), pb = exp2f(s2[3] - m);
    const float pc = exp2f(s3[0] - m), pd = exp2f(s3[1] - m);
    const float pe = exp2f(s3[2] - m), pf = exp2f(s3[3] - m);
    float ls = (((p0 + p1) + (p2 + p3)) + ((p4 + p5) + (p6 + p7))) +
               (((p8 + p9) + (pa + pb)) + ((pc + pd) + (pe + pf)));
    ls += __shfl_xor(ls, 16, 64);
    ls += __shfl_xor(ls, 32, 64);
    l += ls;

    UH ph0, ph1;
    ph0.h2[0] = __builtin_amdgcn_cvt_pkrtz(p0, p1);
    ph0.h2[1] = __builtin_amdgcn_cvt_pkrtz(p2, p3);
    ph0.h2[2] = __builtin_amdgcn_cvt_pkrtz(p4, p5);
    ph0.h2[3] = __builtin_amdgcn_cvt_pkrtz(p6, p7);
    ph1.h2[0] = __builtin_amdgcn_cvt_pkrtz(p8, p9);
    ph1.h2[1] = __builtin_amdgcn_cvt_pkrtz(pa, pb);
    ph1.h2[2] = __builtin_amdgcn_cvt_pkrtz(pc, pd);
    ph1.h2[3] = __builtin_amdgcn_cvt_pkrtz(pe, pf);

    oA = __builtin_amdgcn_mfma_f32_16x16x32_f16(va0, ph0.h8, oA, 0, 0, 0);
    oA = __builtin_amdgcn_mfma_f32_16x16x32_f16(va1, ph1.h8, oA, 0, 0, 0);
    oB = __builtin_amdgcn_mfma_f32_16x16x32_f16(vb0, ph0.h8, oB, 0, 0, 0);
    oB = __builtin_amdgcn_mfma_f32_16x16x32_f16(vb1, ph1.h8, oB, 0, 0, 0);
  }

  // per-wave store into LDS, then block-level combine of the 4 waves
#pragma unroll
  for (int r = 0; r < 4; ++r) {
    lds[wid][(4 * g + r) * 16 + li] = oA[r];
    lds[wid][(16 + 4 * g + r) * 16 + li] = oB[r];
  }
  if (g == 0) {
    lds[wid][512 + li] = m;
    lds[wid][528 + li] = l;
  }
  __syncthreads();
  if (tid < 16) {
    const int q = tid;
    const float m0 = lds[0][512 + q], m1 = lds[1][512 + q];
    const float m2 = lds[2][512 + q], m3 = lds[3][512 + q];
    const float M = fmaxf(fmaxf(m0, m1), fmaxf(m2, m3));
    const float w0 = exp2f(m0 - M), w1 = exp2f(m1 - M);
    const float w2 = exp2f(m2 - M), w3 = exp2f(m3 - M);
    wexp[0][q] = w0; wexp[1][q] = w1; wexp[2][q] = w2; wexp[3][q] = w3;
    Mq[q] = M;
    Lq[q] = w0 * lds[0][528 + q] + w1 * lds[1][528 + q] +
            w2 * lds[2][528 + q] + w3 * lds[3][528 + q];
  }
  __syncthreads();
  const int base = (qtile * 4 + blockIdx.y) * 544;
#pragma unroll
  for (int e2 = 0; e2 < 2; ++e2) {
    const int e = tid + e2 * 256;
    const int q = e & 15;
    part[base + e] = wexp[0][q] * lds[0][e] + wexp[1][q] * lds[1][e] +
                     wexp[2][q] * lds[2][e] + wexp[3][q] * lds[3][e];
  }
  if (tid < 16) {
    part[base + 512 + tid] = Mq[tid];
    part[base + 528 + tid] = Lq[tid];
  }
}

// ---------------- combine partials over 4 ranges + fused wo projection ----------------

__global__ void __launch_bounds__(256) attn_combine_wo(const float* __restrict__ part,
                                                       const float* __restrict__ wo,
                                                       const float* __restrict__ bo,
                                                       float* __restrict__ out) {
  __shared__ float wols[1024];
  __shared__ float bos[32];
  __shared__ float aos[4][16][33];
  const int tid = threadIdx.x;
  for (int i = tid; i < 1024; i += 256) wols[i] = wo[i];
  if (tid < 32) bos[tid] = bo[tid];
  const int wv = tid >> 6, lane = tid & 63;
  const int qt = blockIdx.x * 4 + wv;
  const int q = lane & 15, g = lane >> 4;
  const int pb = qt * 4 * 544;
  const float m0 = part[pb + 512 + q], m1 = part[pb + 544 + 512 + q];
  const float m2 = part[pb + 1088 + 512 + q], m3 = part[pb + 1632 + 512 + q];
  const float M = fmaxf(fmaxf(m0, m1), fmaxf(m2, m3));
  const float w0 = exp2f(m0 - M), w1 = exp2f(m1 - M);
  const float w2 = exp2f(m2 - M), w3 = exp2f(m3 - M);
  const float L = w0 * part[pb + 528 + q] + w1 * part[pb + 544 + 528 + q] +
                  w2 * part[pb + 1088 + 528 + q] + w3 * part[pb + 1632 + 528 + q];
  const float invL = 1.0f / L;
#pragma unroll
  for (int r = 0; r < 8; ++r) {
    const int d = g + 4 * r;
    const int o = d * 16 + q;
    const float ov = w0 * part[pb + o] + w1 * part[pb + 544 + o] +
                     w2 * part[pb + 1088 + o] + w3 * part[pb + 1632 + o];
    aos[wv][q][d] = ov * invL;
  }
  __syncthreads();
#pragma unroll
  for (int r = 0; r < 8; ++r) {
    const int dout = g + 4 * r;
    float acc = bos[dout];
#pragma unroll
    for (int k = 0; k < 32; ++k) acc += aos[wv][q][k] * wols[dout * 32 + k];
    out[(size_t)(qt * 16 + q) * 32 + dout] = acc;
  }
}

// ---------------- launch ----------------

extern "C" void kernel_launch(void* const* d_in, const int* in_sizes, int n_in,
                              void* d_out, int out_size, void* d_ws, size_t ws_size,
                              hipStream_t stream) {
  (void)in_sizes; (void)n_in; (void)out_size; (void)ws_size;
  const int* adj = (const int*)d_in[0];
  const float* feat = (const float*)d_in[1];
  const float* w1 = (const float*)d_in[2];  const float* b1 = (const float*)d_in[3];
  const float* w2 = (const float*)d_in[4];  const float* b2 = (const float*)d_in[5];
  const float* w3 = (const float*)d_in[6];  const float* b3 = (const float*)d_in[7];
  const float* wqkv = (const float*)d_in[8];const float* bqkv = (const float*)d_in[9];
  const float* wo = (const float*)d_in[10]; const float* bo = (const float*)d_in[11];
  const float* w4 = (const float*)d_in[12]; const float* b4 = (const float*)d_in[13];
  const float* w5a = (const float*)d_in[14];const float* b5a = (const float*)d_in[15];
  const float* w6a = (const float*)d_in[16];const float* b6a = (const float*)d_in[17];
  const float* w7a = (const float*)d_in[18];const float* b7a = (const float*)d_in[19];
  const float* w5f = (const float*)d_in[20];const float* b5f = (const float*)d_in[21];
  const float* w6f = (const float*)d_in[22];const float* b6f = (const float*)d_in[23];
  const float* w7f = (const float*)d_in[24];const float* b7f = (const float*)d_in[25];
  float* outp = (float*)d_out;

  float* wsf = (float*)d_ws;
  int* wsi = (int*)d_ws;
  int* cnt = wsi;                 // 8192
  int* cur = wsi + 8192;          // 8192
  int* rp = wsi + 16384;          // 8193
  float* dinv = wsf + 24832;      // 8192
  float* wgt = wsf + 33024;       // 262144
  int* col = wsi + 295168;        // 262144
  float* T = wsf + 557312;        // 8192*128
  float* B0 = wsf + 1605888;      // 8192*64
  float* B1 = wsf + 2130176;      // 8192*32
  float* B2 = wsf + 2392320;      // 8192*64  (end 2916608)
  // fp16 attention buffers: 8192*32 = 262144 ushorts (512 KB) EACH
  unsigned short* Q16 = (unsigned short*)(wsf + 2916608);
  unsigned short* K16 = Q16 + 262144;
  unsigned short* V16 = K16 + 262144;
  float* part = T;  // 512 qtiles x 4 ranges x 544 f32 (spills into dead B0)

  const int* src = adj;
  const int* dst = adj + N_EDGES;

  hipMemsetAsync(cnt, 0, 2 * N_NODES * sizeof(int), stream);  // cnt + cur
  count_kernel<<<N_EDGES / 256, 256, 0, stream>>>(dst, cnt);
  scan_kernel<<<1, 1024, 0, stream>>>(cnt, rp, dinv);
  fill_kernel<<<N_EDGES / 256, 256, 0, stream>>>(src, dst, rp, dinv, cur, col, wgt);

  // gcn1: 128 -> 64 (project then gather 64-wide)
  mm_kernel<128, 64, false, false><<<N_NODES / 16, 256, 0, stream>>>(feat, w1, nullptr, T);
  aggv_kernel<64><<<N_NODES / 4, 256, 0, stream>>>(T, rp, col, wgt, dinv, b1, B0);
  // gcn2: 64 -> 32
  mm_kernel<64, 32, false, false><<<N_NODES / 32, 256, 0, stream>>>(B0, w2, nullptr, T);
  aggv_kernel<32><<<N_NODES / 4, 256, 0, stream>>>(T, rp, col, wgt, dinv, b2, B1);
  // gcn3: 32 -> 32
  mm_kernel<32, 32, false, false><<<N_NODES / 32, 256, 0, stream>>>(B1, w3, nullptr, T);
  aggv_kernel<32><<<N_NODES / 4, 256, 0, stream>>>(T, rp, col, wgt, dinv, b3, B0);  // h3 in B0

  // attention (fp16 MFMA flash, KSPLIT=4, in-block wave combine)
  qkv_kernel<<<N_NODES / 8, 256, 0, stream>>>(B0, wqkv, bqkv, Q16, K16, V16);
  {
    dim3 grid(512, 4);
    attn_mfma_kernel<<<grid, 256, 0, stream>>>(Q16, K16, V16, part);
  }
  attn_combine_wo<<<128, 256, 0, stream>>>(part, wo, bo, B2);  // h_attn in B2

  // gcn4: 32 -> 32
  mm_kernel<32, 32, false, false><<<N_NODES / 32, 256, 0, stream>>>(B2, w4, nullptr, T);
  aggv_kernel<32><<<N_NODES / 4, 256, 0, stream>>>(T, rp, col, wgt, dinv, b4, B0);  // h4 in B0

  // da head: 32->32->64->2
  mm_kernel<32, 32, false, false><<<N_NODES / 32, 256, 0, stream>>>(B0, w5a, nullptr, T);
  aggv_kernel<32><<<N_NODES / 4, 256, 0, stream>>>(T, rp, col, wgt, dinv, b5a, B1);
  // gcn6a expanded (32->64): gather 32-wide FIRST, then project with bias+relu
  aggv_kernel<32, false><<<N_NODES / 4, 256, 0, stream>>>(B1, rp, col, wgt, dinv, nullptr, T);
  mm_kernel<32, 64, false, true, true><<<N_NODES / 16, 256, 0, stream>>>(T, w6a, b6a, B2);
  // gcn7a (64->2): project then gather
  mm_kernel<64, 2, false, false><<<N_NODES / 128, 256, 0, stream>>>(B2, w7a, nullptr, T);
  agg_kernel<2><<<N_NODES / 128, 256, 0, stream>>>(T, rp, col, wgt, dinv, b7a, outp);

  // df head: 32->32->64->128
  mm_kernel<32, 32, false, false><<<N_NODES / 32, 256, 0, stream>>>(B0, w5f, nullptr, T);
  aggv_kernel<32><<<N_NODES / 4, 256, 0, stream>>>(T, rp, col, wgt, dinv, b5f, B1);
  // gcn6f (32->64): gather first
  aggv_kernel<32, false><<<N_NODES / 4, 256, 0, stream>>>(B1, rp, col, wgt, dinv, nullptr, T);
  mm_kernel<32, 64, false, true, true><<<N_NODES / 16, 256, 0, stream>>>(T, w6f, b6f, B2);
  // gcn7f (64->128): gather first (64-wide), then project 64->128 with bias+relu
  aggv_kernel<64, false><<<N_NODES / 4, 256, 0, stream>>>(B2, rp, col, wgt, dinv, nullptr, T);
  mm_kernel<64, 128, false, true, true><<<N_NODES / 8, 256, 0, stream>>>(T, w7f, b7f, outp + 16384);
}